// Round 4
// baseline (1462.975 us; speedup 1.0000x reference)
//
#include <hip/hip_runtime.h>

typedef unsigned short u16;
typedef unsigned int u32;
typedef __attribute__((ext_vector_type(8))) short short8;
typedef __attribute__((ext_vector_type(4))) float floatx4;

#define E_EDGES 24576
#define EC 12288            // edge chunk
#define N_NODES_C 4096

__device__ __forceinline__ float bf2f(u16 u) {
    union { u32 i; float f; } v; v.i = ((u32)u) << 16; return v.f;
}
__device__ __forceinline__ u16 f2bf(float f) {
    union { float f; u32 i; } v; v.f = f;
    u32 x = v.i;
    u32 r = (x + 0x7fffu + ((x >> 16) & 1u)) >> 16;
    return (u16)r;
}
__device__ __forceinline__ u32 encf(float f) {
    union { float f; u32 i; } v; v.f = f;
    return (v.i & 0x80000000u) ? ~v.i : (v.i | 0x80000000u);
}
__device__ __forceinline__ float decf(u32 u) {
    union { u32 i; float f; } v;
    v.i = (u & 0x80000000u) ? (u ^ 0x80000000u) : ~u;
    return v.f;
}
__device__ __forceinline__ float sigmoidf_(float x) { return 1.f / (1.f + expf(-x)); }
__device__ __forceinline__ float siluf_(float x) { return x / (1.f + expf(-x)); }

// diagnostic: ws too small -> paint output with 1000 (f32!)
__global__ void k_diag(float* __restrict__ out, int n) {
    int i = blockIdx.x * 256 + threadIdx.x;
    if (i < n) out[i] = 1000.0f;
}

// ---------------- weight prep (f32 src -> bf16 transposed) ----------------
__global__ void k_transpose(const float* __restrict__ src, u16* __restrict__ dst, int K, int N) {
    int idx = blockIdx.x * 256 + threadIdx.x;
    if (idx >= K * N) return;
    int k = idx / N, n = idx % N;
    dst[n * K + k] = f2bf(src[idx]);
}
// combined complex weight, pre-transposed. src (K, 2H) f32: wa=cols[0:H), wb=cols[H:2H).
// dst (2H, 2K) bf16: dst[n][k] = k<K ? src[k][n] : (n<H ? -src[k-K][H+n] : src[k-K][n-H])
__global__ void k_combine(const float* __restrict__ src, u16* __restrict__ dst, int K, int H) {
    int total = 4 * K * H;
    int idx = blockIdx.x * 256 + threadIdx.x;
    if (idx >= total) return;
    int n = idx / (2 * K), k = idx % (2 * K);
    float v;
    if (k < K) v = src[k * 2 * H + n];
    else {
        int kk = k - K;
        if (n < H) v = -src[kk * 2 * H + H + n];
        else       v = src[kk * 2 * H + (n - H)];
    }
    dst[idx] = f2bf(v);
}

__global__ void k_init(u32* __restrict__ nmax, float* __restrict__ nsum, int n) {
    int idx = blockIdx.x * 256 + threadIdx.x;
    if (idx < n) { nmax[idx] = 0x007FFFFFu; /* enc(-inf) */ nsum[idx] = 0.f; }
}

// ---------------- edge embeddings (f32 in -> bf16 A) ----------------
__global__ void k_ee(const float* __restrict__ dist, const int* __restrict__ species,
                     const int* __restrict__ snd, const int* __restrict__ rcv,
                     const float* __restrict__ semb, const float* __restrict__ remb,
                     u16* __restrict__ ee) {
    int idx = blockIdx.x * 256 + threadIdx.x;
    if (idx >= E_EDGES * 192) return;
    int e = idx / 192, c = idx % 192;
    float v;
    if (c < 64)       v = dist[e * 64 + c];
    else if (c < 128) v = semb[species[snd[e]] * 64 + (c - 64)];
    else              v = remb[species[rcv[e]] * 64 + (c - 128)];
    ee[idx] = f2bf(v);
}

// ---------------- GEMM: A (M,K) bf16 rm, BT (N,K) bf16 rm, C (M,N) bf16, bias f32 ----------------
// M % 128 == 0, K % 32 == 0 by construction; N guarded.
#define LSTR 40
__global__ __launch_bounds__(256) void k_gemm(
    const u16* __restrict__ A, int lda,
    const u16* __restrict__ BT, int ldb,
    u16* __restrict__ C, int ldc,
    int N, int K,
    const float* __restrict__ bias) {
    __shared__ u16 As[128 * LSTR];
    __shared__ u16 Bs[128 * LSTR];
    int tid = threadIdx.x;
    int bm0 = blockIdx.x * 128;
    int bn0 = blockIdx.y * 128;
    int wave = tid >> 6, lane = tid & 63;
    int wm = (wave >> 1) * 64, wn = (wave & 1) * 64;
    int lrow = lane & 15, lk = (lane >> 4) * 8;

    floatx4 acc[4][4];
#pragma unroll
    for (int i = 0; i < 4; i++)
#pragma unroll
        for (int j = 0; j < 4; j++) acc[i][j] = floatx4{0.f, 0.f, 0.f, 0.f};

    int sr = tid >> 1;          // 0..127
    int sk = (tid & 1) * 16;    // 0 or 16

    for (int k0 = 0; k0 < K; k0 += 32) {
        {
            const uint4* src = (const uint4*)(A + (size_t)(bm0 + sr) * lda + k0 + sk);
            uint4 v0 = src[0];
            uint4 v1 = src[1];
            *(uint4*)(&As[sr * LSTR + sk]) = v0;
            *(uint4*)(&As[sr * LSTR + sk + 8]) = v1;
        }
        {
            int n = bn0 + sr; if (n >= N) n = N - 1;
            const uint4* src = (const uint4*)(BT + (size_t)n * ldb + k0 + sk);
            uint4 v0 = src[0];
            uint4 v1 = src[1];
            *(uint4*)(&Bs[sr * LSTR + sk]) = v0;
            *(uint4*)(&Bs[sr * LSTR + sk + 8]) = v1;
        }
        __syncthreads();
        short8 a[4], b[4];
#pragma unroll
        for (int i = 0; i < 4; i++) a[i] = *(const short8*)(&As[(wm + i * 16 + lrow) * LSTR + lk]);
#pragma unroll
        for (int j = 0; j < 4; j++) b[j] = *(const short8*)(&Bs[(wn + j * 16 + lrow) * LSTR + lk]);
#pragma unroll
        for (int i = 0; i < 4; i++)
#pragma unroll
            for (int j = 0; j < 4; j++)
                acc[i][j] = __builtin_amdgcn_mfma_f32_16x16x32_bf16(a[i], b[j], acc[i][j], 0, 0, 0);
        __syncthreads();
    }

    int q = lane >> 4;
#pragma unroll
    for (int i = 0; i < 4; i++) {
#pragma unroll
        for (int j = 0; j < 4; j++) {
            int col = bn0 + wn + j * 16 + lrow;
            if (col < N) {
                float bv = bias ? bias[col] : 0.f;
#pragma unroll
                for (int r = 0; r < 4; r++) {
                    int row = bm0 + wm + i * 16 + q * 4 + r;
                    C[(size_t)row * ldc + col] = f2bf(acc[i][j][r] + bv);
                }
            }
        }
    }
}

// ---------------- LayerNorm(64) + SiLU (bf16 io, f32 params) ----------------
__global__ __launch_bounds__(256) void k_ln_silu(const u16* __restrict__ in, u16* __restrict__ out,
                                                 const float* __restrict__ g, const float* __restrict__ b) {
    int tid = threadIdx.x;
    int e = blockIdx.x * 4 + (tid >> 6);
    int c = tid & 63;
    float x = bf2f(in[(size_t)e * 64 + c]);
    float s = x, s2 = x * x;
#pragma unroll
    for (int o = 32; o; o >>= 1) { s += __shfl_xor(s, o); s2 += __shfl_xor(s2, o); }
    float mu = s * (1.f / 64.f);
    float var = s2 * (1.f / 64.f) - mu * mu;
    float rs = rsqrtf(var + 1e-5f);
    float y = (x - mu) * rs * g[c] + b[c];
    out[(size_t)e * 64 + c] = f2bf(siluf_(y));
}

// ---------------- rotate: wigner @ concat(nf[snd],nf[rcv]); scale by x_edge; pack A1 (chunked) ----------------
__global__ __launch_bounds__(256) void k_rotate(const float* __restrict__ nf, const float* __restrict__ wig,
                                                const int* __restrict__ snd, const int* __restrict__ rcv,
                                                const u16* __restrict__ xe, u16* __restrict__ A1, int e0) {
    __shared__ float wl[2][475];
    int tid = threadIdx.x;
    for (int i = tid; i < 950; i += 256) {
        int ee = e0 + blockIdx.x * 2 + (i / 475);
        wl[i / 475][i % 475] = wig[(size_t)ee * 475 + (i % 475)];
    }
    __syncthreads();
    int le = tid >> 7, c = tid & 127;
    int el = blockIdx.x * 2 + le;       // chunk-local
    int e = e0 + el;                    // global
    int nd = (c < 64) ? snd[e] : rcv[e];
    int cc = c & 63;
    float msg[25];
#pragma unroll
    for (int k = 0; k < 25; k++) msg[k] = nf[(size_t)nd * 1600 + k * 64 + cc];
    const float* w = wl[le];
    size_t ebase = (size_t)el * 2432;
    size_t xbase = (size_t)el * 1536;
#pragma unroll
    for (int m = 0; m < 19; m++) {
        float r = 0.f;
#pragma unroll
        for (int k = 0; k < 25; k++) r += w[m * 25 + k] * msg[k];
        int a1c, xc;
        if (m < 5)       { a1c = m * 128;               xc = m * 128; }
        else if (m < 9)  { a1c = 640 + (m - 5) * 128;   xc = 640 + (m - 5) * 128; }
        else if (m < 13) { a1c = 1152 + (m - 9) * 128;  xc = 640 + (m - 9) * 128; }
        else if (m < 16) { a1c = 1664 + (m - 13) * 128; xc = 1152 + (m - 13) * 128; }
        else             { a1c = 2048 + (m - 16) * 128; xc = 1152 + (m - 16) * 128; }
        float sc = bf2f(xe[xbase + xc + c]);
        A1[ebase + a1c + c] = f2bf(r * sc);
    }
}

// ---------------- attention logits + segment max ----------------
__global__ __launch_bounds__(256) void k_logits(const u16* __restrict__ Y0, const int* __restrict__ rcv,
                                                const float* __restrict__ g, const float* __restrict__ b,
                                                const float* __restrict__ adot,
                                                float* __restrict__ logits, u32* __restrict__ nmax) {
    int e = blockIdx.x;
    int tid = threadIdx.x;
    int h = tid >> 5, c = tid & 31;
    float x = bf2f(Y0[(size_t)e * 640 + 320 + h * 32 + c]);
    float s = x, s2 = x * x;
#pragma unroll
    for (int o = 16; o; o >>= 1) { s += __shfl_xor(s, o); s2 += __shfl_xor(s2, o); }
    float mu = s * (1.f / 32.f);
    float var = s2 * (1.f / 32.f) - mu * mu;
    float rs = rsqrtf(var + 1e-5f);
    float a = (x - mu) * rs * g[c] + b[c];
    float f = 0.6f * a + 0.4f * a * (2.f * sigmoidf_(a) - 1.f);
    float l = f * adot[h * 32 + c];
#pragma unroll
    for (int o = 16; o; o >>= 1) l += __shfl_xor(l, o);
    if (c == 0) {
        logits[e * 8 + h] = l;
        atomicMax(&nmax[rcv[e] * 8 + h], encf(l));
    }
}

__global__ void k_expsum(const float* __restrict__ logits, const int* __restrict__ rcv,
                         const u32* __restrict__ nmax, float* __restrict__ ealpha, float* __restrict__ nsum) {
    int idx = blockIdx.x * 256 + threadIdx.x;
    if (idx >= E_EDGES * 8) return;
    int e = idx >> 3, h = idx & 7;
    int r = rcv[e];
    float amax = decf(nmax[r * 8 + h]);
    if (!(amax > -1e38f && amax < 1e38f)) amax = 0.f;
    float v = expf(logits[idx] - amax);
    ealpha[idx] = v;
    atomicAdd(&nsum[r * 8 + h], v);
}

// ---------------- grid round-trip: tens = from_grid @ silu(to_grid @ msgs1); pack A2 ----------------
__global__ __launch_bounds__(256) void k_grid(const u16* __restrict__ Y0, const u16* __restrict__ Y1,
                                              const u16* __restrict__ Y2, const float* __restrict__ tg,
                                              const float* __restrict__ fg, u16* __restrict__ A2) {
    __shared__ float tgl[1900];
    __shared__ float fgl[1900];
    int tid = threadIdx.x;
    for (int i = tid; i < 1900; i += 256) { tgl[i] = tg[i]; fgl[i] = fg[i]; }
    __syncthreads();
    int e = blockIdx.x * 4 + (tid >> 6);
    int c = tid & 63;
    float x[19];
#pragma unroll
    for (int m = 0; m < 19; m++) {
        if (m < 5)       x[m] = bf2f(Y0[(size_t)e * 640 + m * 64 + c]);
        else if (m < 13) x[m] = bf2f(Y1[(size_t)e * 512 + (m - 5) * 64 + c]);
        else             x[m] = bf2f(Y2[(size_t)e * 384 + (m - 13) * 64 + c]);
    }
    float t[19];
#pragma unroll
    for (int m = 0; m < 19; m++) t[m] = 0.f;
    for (int p = 0; p < 100; p++) {
        float gs = 0.f;
#pragma unroll
        for (int m = 0; m < 19; m++) gs += tgl[p * 19 + m] * x[m];
        float sv = siluf_(gs);
#pragma unroll
        for (int m = 0; m < 19; m++) t[m] += fgl[m * 100 + p] * sv;
    }
    size_t base = (size_t)e * 1216;
    float gate = bf2f(Y0[(size_t)e * 640 + 576 + c]);
    A2[base + c] = f2bf(siluf_(gate));
#pragma unroll
    for (int m = 1; m < 19; m++) A2[base + m * 64 + c] = f2bf(t[m]);
}

// ---------------- attention scale + wigner^T + segment-sum into node (chunked) ----------------
__global__ __launch_bounds__(256) void k_scatter(const u16* __restrict__ Z0, const u16* __restrict__ Z1,
                                                 const u16* __restrict__ Z2, const float* __restrict__ wig,
                                                 const float* __restrict__ ealpha, const float* __restrict__ nsum,
                                                 const int* __restrict__ rcv, float* __restrict__ node, int e0) {
    __shared__ float wl[2][475];
    int tid = threadIdx.x;
    for (int i = tid; i < 950; i += 256) {
        int ee = e0 + blockIdx.x * 2 + (i / 475);
        wl[i / 475][i % 475] = wig[(size_t)ee * 475 + (i % 475)];
    }
    __syncthreads();
    int le = tid >> 7, c = tid & 127;
    int el = blockIdx.x * 2 + le;
    int e = e0 + el;
    int r = rcv[e];
    int h = c >> 4;
    float al = ealpha[e * 8 + h] / (nsum[r * 8 + h] + 1e-16f);
    float s[19];
#pragma unroll
    for (int m = 0; m < 19; m++) {
        float v;
        if (m < 5)       v = bf2f(Z0[(size_t)el * 640 + m * 128 + c]);
        else if (m < 13) v = bf2f(Z1[(size_t)el * 1024 + (m - 5) * 128 + c]);
        else             v = bf2f(Z2[(size_t)el * 768 + (m - 13) * 128 + c]);
        s[m] = v * al;
    }
    const float* w = wl[le];
    float* nb = node + (size_t)r * 3200 + c;
#pragma unroll
    for (int k = 0; k < 25; k++) {
        float acc = 0.f;
#pragma unroll
        for (int m = 0; m < 19; m++) acc += w[m * 25 + k] * s[m];
        atomicAdd(&nb[k * 128], acc);
    }
}

// ---------------- final projection (f32 node, f32 weights, f32 out) ----------------
__global__ void k_proj(const float* __restrict__ node, const float* __restrict__ pw,
                       const float* __restrict__ pb, float* __restrict__ out) {
    int n = blockIdx.x;
    int tid = threadIdx.x;
    int d = tid & 63, kk = tid >> 6;
    for (int k = kk; k < 25; k += 4) {
        int l = (int)sqrtf((float)k + 0.5f);
        const float* nr = node + (size_t)n * 3200 + k * 128;
        const float* w = pw + (size_t)l * 8192 + d;
        float acc = 0.f;
#pragma unroll 8
        for (int c = 0; c < 128; c++) acc += nr[c] * w[c * 64];
        if (k == 0) acc += pb[d];
        out[(size_t)n * 1600 + k * 64 + d] = acc;   // f32 store — the round-4 fix
    }
}

extern "C" void kernel_launch(void* const* d_in, const int* in_sizes, int n_in,
                              void* d_out, int out_size, void* d_ws, size_t ws_size,
                              hipStream_t stream) {
    const float* nf      = (const float*)d_in[0];
    const int* species   = (const int*)d_in[1];
    const float* dist    = (const float*)d_in[2];
    const int* snd       = (const int*)d_in[3];
    const int* rcv       = (const int*)d_in[4];
    const float* wig     = (const float*)d_in[5];
    const float* semb    = (const float*)d_in[6];
    const float* remb    = (const float*)d_in[7];
    const float* rad_w1  = (const float*)d_in[8];
    const float* rad_b1  = (const float*)d_in[9];
    const float* rad_g1  = (const float*)d_in[10];
    const float* rad_be1 = (const float*)d_in[11];
    const float* rad_w2  = (const float*)d_in[12];
    const float* rad_b2  = (const float*)d_in[13];
    const float* rad_g2  = (const float*)d_in[14];
    const float* rad_be2 = (const float*)d_in[15];
    const float* rad_w3  = (const float*)d_in[16];
    const float* rad_b3  = (const float*)d_in[17];
    const float* c1_w0   = (const float*)d_in[18];
    const float* c1_b0   = (const float*)d_in[19];
    const float* c1_wm1  = (const float*)d_in[20];
    const float* c1_wm2  = (const float*)d_in[21];
    const float* aln_g   = (const float*)d_in[22];
    const float* aln_b   = (const float*)d_in[23];
    const float* adot    = (const float*)d_in[24];
    const float* to_grid = (const float*)d_in[25];
    const float* from_grid=(const float*)d_in[26];
    const float* c2_w0   = (const float*)d_in[27];
    const float* c2_b0   = (const float*)d_in[28];
    const float* c2_wm1  = (const float*)d_in[29];
    const float* c2_wm2  = (const float*)d_in[30];
    const float* proj_w  = (const float*)d_in[31];
    const float* proj_b  = (const float*)d_in[32];

    char* ws = (char*)d_ws;
    size_t off = 0;
    auto take = [&](size_t bytes) -> char* {
        char* p = ws + off;
        off += (bytes + 255) & ~(size_t)255;
        return p;
    };
    // fixed section
    u16* w_rad1T  = (u16*)take(64 * 192 * 2);
    u16* w_rad2T  = (u16*)take(64 * 64 * 2);
    u16* w_rad3T  = (u16*)take(1536 * 64 * 2);
    u16* w_c1w0T  = (u16*)take(640 * 640 * 2);
    u16* w_c1m1T  = (u16*)take((size_t)512 * 1024 * 2);
    u16* w_c1m2T  = (u16*)take((size_t)384 * 768 * 2);
    u16* w_c2w0T  = (u16*)take((size_t)640 * 320 * 2);
    u16* w_c2m1T  = (u16*)take((size_t)1024 * 512 * 2);
    u16* w_c2m2T  = (u16*)take((size_t)768 * 384 * 2);
    float* logits = (float*)take((size_t)E_EDGES * 8 * 4);
    float* ealpha = (float*)take((size_t)E_EDGES * 8 * 4);
    u32* nmax     = (u32*)take((size_t)N_NODES_C * 8 * 4);
    float* nsum   = (float*)take((size_t)N_NODES_C * 8 * 4);
    float* node   = (float*)take((size_t)N_NODES_C * 3200 * 4);
    u16* a_h2     = (u16*)take((size_t)E_EDGES * 64 * 2);
    // arena — aliased by phase
    char* arena   = take(173015040);
    if (off > ws_size) {  // diagnostic: paint output so the failure mode is identifiable
        k_diag<<<(out_size + 255) / 256, 256, 0, stream>>>((float*)d_out, out_size);
        return;
    }

    u16* a_ee   = (u16*)(arena + 0);           // radial phase
    u16* a_ypre = (u16*)(arena + 9437184);
    u16* a_h1   = (u16*)(arena + 12582912);
    u16* a_xe   = (u16*)(arena + 0);           // per-chunk (EC,1536); radial staging dead
    u16* a_A1   = (u16*)(arena + 37748736);    // per-chunk (EC,2432)
    u16* a_Y0   = (u16*)(arena + 97517568);    // full (E,640)
    u16* a_Y1   = (u16*)(arena + 128974848);   // full (E,512)
    u16* a_Y2   = (u16*)(arena + 154140672);   // full (E,384) -> arena end
    u16* a_A2   = (u16*)(arena + 0);           // full (E,1216); xe/A1 dead
    u16* a_Z0   = (u16*)(arena + 59768832);    // per-chunk (EC,640)
    u16* a_Z1   = (u16*)(arena + 75497472);    // per-chunk (EC,1024)
    u16* a_Z2   = (u16*)(arena + 100663296);   // per-chunk (EC,768); overlaps dead Y0 region

    // ---- weight prep ----
    k_transpose<<<48, 256, 0, stream>>>(rad_w1, w_rad1T, 192, 64);
    k_transpose<<<16, 256, 0, stream>>>(rad_w2, w_rad2T, 64, 64);
    k_transpose<<<384, 256, 0, stream>>>(rad_w3, w_rad3T, 64, 1536);
    k_transpose<<<1600, 256, 0, stream>>>(c1_w0, w_c1w0T, 640, 640);
    k_transpose<<<800, 256, 0, stream>>>(c2_w0, w_c2w0T, 320, 640);
    k_combine<<<2048, 256, 0, stream>>>(c1_wm1, w_c1m1T, 512, 256);
    k_combine<<<1152, 256, 0, stream>>>(c1_wm2, w_c1m2T, 384, 192);
    k_combine<<<2048, 256, 0, stream>>>(c2_wm1, w_c2m1T, 256, 512);
    k_combine<<<1152, 256, 0, stream>>>(c2_wm2, w_c2m2T, 192, 384);
    k_init<<<128, 256, 0, stream>>>(nmax, nsum, N_NODES_C * 8);
    hipMemsetAsync(node, 0, (size_t)N_NODES_C * 3200 * 4, stream);

    // ---- radial MLP (full E) ----
    k_ee<<<(E_EDGES * 192 + 255) / 256, 256, 0, stream>>>(dist, species, snd, rcv, semb, remb, a_ee);
    k_gemm<<<dim3(192, 1), 256, 0, stream>>>(a_ee, 192, w_rad1T, 192, a_ypre, 64, 64, 192, rad_b1);
    k_ln_silu<<<6144, 256, 0, stream>>>(a_ypre, a_h1, rad_g1, rad_be1);
    k_gemm<<<dim3(192, 1), 256, 0, stream>>>(a_h1, 64, w_rad2T, 64, a_ypre, 64, 64, 64, rad_b2);
    k_ln_silu<<<6144, 256, 0, stream>>>(a_ypre, a_h2, rad_g2, rad_be2);

    // ---- chunked: x_edge gemm -> rotate -> conv1 ----
    for (int c = 0; c < 2; c++) {
        int e0 = c * EC;
        k_gemm<<<dim3(96, 12), 256, 0, stream>>>(a_h2 + (size_t)e0 * 64, 64, w_rad3T, 64,
                                                 a_xe, 1536, 1536, 64, rad_b3);
        k_rotate<<<EC / 2, 256, 0, stream>>>(nf, wig, snd, rcv, a_xe, a_A1, e0);
        k_gemm<<<dim3(96, 5), 256, 0, stream>>>(a_A1, 2432, w_c1w0T, 640,
                                                a_Y0 + (size_t)e0 * 640, 640, 640, 640, c1_b0);
        k_gemm<<<dim3(96, 4), 256, 0, stream>>>(a_A1 + 640, 2432, w_c1m1T, 1024,
                                                a_Y1 + (size_t)e0 * 512, 512, 512, 1024, nullptr);
        k_gemm<<<dim3(96, 3), 256, 0, stream>>>(a_A1 + 1664, 2432, w_c1m2T, 768,
                                                a_Y2 + (size_t)e0 * 384, 384, 384, 768, nullptr);
    }

    // ---- attention softmax pieces ----
    k_logits<<<E_EDGES, 256, 0, stream>>>(a_Y0, rcv, aln_g, aln_b, adot, logits, nmax);
    k_expsum<<<(E_EDGES * 8 + 255) / 256, 256, 0, stream>>>(logits, rcv, nmax, ealpha, nsum);

    // ---- grid nonlinearity -> packed A2 (full E) ----
    k_grid<<<6144, 256, 0, stream>>>(a_Y0, a_Y1, a_Y2, to_grid, from_grid, a_A2);

    // ---- chunked: conv2 -> scatter ----
    for (int c = 0; c < 2; c++) {
        int e0 = c * EC;
        k_gemm<<<dim3(96, 5), 256, 0, stream>>>(a_A2 + (size_t)e0 * 1216, 1216, w_c2w0T, 320,
                                                a_Z0, 640, 640, 320, c2_b0);
        k_gemm<<<dim3(96, 8), 256, 0, stream>>>(a_A2 + (size_t)e0 * 1216 + 320, 1216, w_c2m1T, 512,
                                                a_Z1, 1024, 1024, 512, nullptr);
        k_gemm<<<dim3(96, 6), 256, 0, stream>>>(a_A2 + (size_t)e0 * 1216 + 832, 1216, w_c2m2T, 384,
                                                a_Z2, 768, 768, 384, nullptr);
        k_scatter<<<EC / 2, 256, 0, stream>>>(a_Z0, a_Z1, a_Z2, wig, ealpha, nsum, rcv, node, e0);
    }

    // ---- output projection ----
    k_proj<<<N_NODES_C, 256, 0, stream>>>(node, proj_w, proj_b, (float*)d_out);
}

// Round 5
// 1332.082 us; speedup vs baseline: 1.0983x; 1.0983x over previous
//
#include <hip/hip_runtime.h>

typedef unsigned short u16;
typedef unsigned int u32;
typedef __attribute__((ext_vector_type(8))) short short8;
typedef __attribute__((ext_vector_type(4))) float floatx4;

#define E_EDGES 24576
#define EC 12288            // edge chunk
#define N_NODES_C 4096

__device__ __forceinline__ float bf2f(u16 u) {
    union { u32 i; float f; } v; v.i = ((u32)u) << 16; return v.f;
}
__device__ __forceinline__ u16 f2bf(float f) {
    union { float f; u32 i; } v; v.f = f;
    u32 x = v.i;
    u32 r = (x + 0x7fffu + ((x >> 16) & 1u)) >> 16;
    return (u16)r;
}
__device__ __forceinline__ u32 encf(float f) {
    union { float f; u32 i; } v; v.f = f;
    return (v.i & 0x80000000u) ? ~v.i : (v.i | 0x80000000u);
}
__device__ __forceinline__ float decf(u32 u) {
    union { u32 i; float f; } v;
    v.i = (u & 0x80000000u) ? (u ^ 0x80000000u) : ~u;
    return v.f;
}
__device__ __forceinline__ float sigmoidf_(float x) { return 1.f / (1.f + expf(-x)); }
__device__ __forceinline__ float siluf_(float x) { return x / (1.f + expf(-x)); }

// diagnostic: ws too small -> paint output with 1000 (f32)
__global__ void k_diag(float* __restrict__ out, int n) {
    int i = blockIdx.x * 256 + threadIdx.x;
    if (i < n) out[i] = 1000.0f;
}

// ---------------- weight prep (f32 src -> bf16 transposed) ----------------
__global__ void k_transpose(const float* __restrict__ src, u16* __restrict__ dst, int K, int N) {
    int idx = blockIdx.x * 256 + threadIdx.x;
    if (idx >= K * N) return;
    int k = idx / N, n = idx % N;
    dst[n * K + k] = f2bf(src[idx]);
}
// combined complex weight, pre-transposed. src (K, 2H) f32: wa=cols[0:H), wb=cols[H:2H).
// dst (2H, 2K) bf16: dst[n][k] = k<K ? src[k][n] : (n<H ? -src[k-K][H+n] : src[k-K][n-H])
__global__ void k_combine(const float* __restrict__ src, u16* __restrict__ dst, int K, int H) {
    int total = 4 * K * H;
    int idx = blockIdx.x * 256 + threadIdx.x;
    if (idx >= total) return;
    int n = idx / (2 * K), k = idx % (2 * K);
    float v;
    if (k < K) v = src[k * 2 * H + n];
    else {
        int kk = k - K;
        if (n < H) v = -src[kk * 2 * H + H + n];
        else       v = src[kk * 2 * H + (n - H)];
    }
    dst[idx] = f2bf(v);
}

// pack to_grid (100,19) -> tgP[112][32] bf16 ([p][m], padded zeros);
// pack from_grid (19,100) -> fgP[32][128] bf16 ([m'][p], padded zeros)
__global__ void k_packgrid(const float* __restrict__ tg, const float* __restrict__ fg,
                           u16* __restrict__ tgP, u16* __restrict__ fgP) {
    int idx = blockIdx.x * 256 + threadIdx.x;
    if (idx < 112 * 32) {
        int p = idx >> 5, m = idx & 31;
        tgP[idx] = (p < 100 && m < 19) ? f2bf(tg[p * 19 + m]) : (u16)0;
    }
    int j = idx - 112 * 32;
    if (j >= 0 && j < 32 * 128) {
        int m = j >> 7, k = j & 127;
        fgP[j] = (m < 19 && k < 100) ? f2bf(fg[m * 100 + k]) : (u16)0;
    }
}

__global__ void k_init(u32* __restrict__ nmax, float* __restrict__ nsum, int n) {
    int idx = blockIdx.x * 256 + threadIdx.x;
    if (idx < n) { nmax[idx] = 0x007FFFFFu; /* enc(-inf) */ nsum[idx] = 0.f; }
}

// ---------------- edge embeddings (f32 in -> bf16 A) ----------------
__global__ void k_ee(const float* __restrict__ dist, const int* __restrict__ species,
                     const int* __restrict__ snd, const int* __restrict__ rcv,
                     const float* __restrict__ semb, const float* __restrict__ remb,
                     u16* __restrict__ ee) {
    int idx = blockIdx.x * 256 + threadIdx.x;
    if (idx >= E_EDGES * 192) return;
    int e = idx / 192, c = idx % 192;
    float v;
    if (c < 64)       v = dist[e * 64 + c];
    else if (c < 128) v = semb[species[snd[e]] * 64 + (c - 64)];
    else              v = remb[species[rcv[e]] * 64 + (c - 128)];
    ee[idx] = f2bf(v);
}

// ---------------- GEMM: A (M,K) bf16 rm, BT (N,K) bf16 rm, C (M,N) bf16, bias f32 ----------------
// M % 128 == 0, K % 32 == 0 by construction; N guarded.
#define LSTR 40
__global__ __launch_bounds__(256) void k_gemm(
    const u16* __restrict__ A, int lda,
    const u16* __restrict__ BT, int ldb,
    u16* __restrict__ C, int ldc,
    int N, int K,
    const float* __restrict__ bias) {
    __shared__ u16 As[128 * LSTR];
    __shared__ u16 Bs[128 * LSTR];
    int tid = threadIdx.x;
    int bm0 = blockIdx.x * 128;
    int bn0 = blockIdx.y * 128;
    int wave = tid >> 6, lane = tid & 63;
    int wm = (wave >> 1) * 64, wn = (wave & 1) * 64;
    int lrow = lane & 15, lk = (lane >> 4) * 8;

    floatx4 acc[4][4];
#pragma unroll
    for (int i = 0; i < 4; i++)
#pragma unroll
        for (int j = 0; j < 4; j++) acc[i][j] = floatx4{0.f, 0.f, 0.f, 0.f};

    int sr = tid >> 1;          // 0..127
    int sk = (tid & 1) * 16;    // 0 or 16

    for (int k0 = 0; k0 < K; k0 += 32) {
        {
            const uint4* src = (const uint4*)(A + (size_t)(bm0 + sr) * lda + k0 + sk);
            uint4 v0 = src[0];
            uint4 v1 = src[1];
            *(uint4*)(&As[sr * LSTR + sk]) = v0;
            *(uint4*)(&As[sr * LSTR + sk + 8]) = v1;
        }
        {
            int n = bn0 + sr; if (n >= N) n = N - 1;
            const uint4* src = (const uint4*)(BT + (size_t)n * ldb + k0 + sk);
            uint4 v0 = src[0];
            uint4 v1 = src[1];
            *(uint4*)(&Bs[sr * LSTR + sk]) = v0;
            *(uint4*)(&Bs[sr * LSTR + sk + 8]) = v1;
        }
        __syncthreads();
        short8 a[4], b[4];
#pragma unroll
        for (int i = 0; i < 4; i++) a[i] = *(const short8*)(&As[(wm + i * 16 + lrow) * LSTR + lk]);
#pragma unroll
        for (int j = 0; j < 4; j++) b[j] = *(const short8*)(&Bs[(wn + j * 16 + lrow) * LSTR + lk]);
#pragma unroll
        for (int i = 0; i < 4; i++)
#pragma unroll
            for (int j = 0; j < 4; j++)
                acc[i][j] = __builtin_amdgcn_mfma_f32_16x16x32_bf16(a[i], b[j], acc[i][j], 0, 0, 0);
        __syncthreads();
    }

    int q = lane >> 4;
#pragma unroll
    for (int i = 0; i < 4; i++) {
#pragma unroll
        for (int j = 0; j < 4; j++) {
            int col = bn0 + wn + j * 16 + lrow;
            if (col < N) {
                float bv = bias ? bias[col] : 0.f;
#pragma unroll
                for (int r = 0; r < 4; r++) {
                    int row = bm0 + wm + i * 16 + q * 4 + r;
                    C[(size_t)row * ldc + col] = f2bf(acc[i][j][r] + bv);
                }
            }
        }
    }
}

// ---------------- LayerNorm(64) + SiLU (bf16 io, f32 params) ----------------
__global__ __launch_bounds__(256) void k_ln_silu(const u16* __restrict__ in, u16* __restrict__ out,
                                                 const float* __restrict__ g, const float* __restrict__ b) {
    int tid = threadIdx.x;
    int e = blockIdx.x * 4 + (tid >> 6);
    int c = tid & 63;
    float x = bf2f(in[(size_t)e * 64 + c]);
    float s = x, s2 = x * x;
#pragma unroll
    for (int o = 32; o; o >>= 1) { s += __shfl_xor(s, o); s2 += __shfl_xor(s2, o); }
    float mu = s * (1.f / 64.f);
    float var = s2 * (1.f / 64.f) - mu * mu;
    float rs = rsqrtf(var + 1e-5f);
    float y = (x - mu) * rs * g[c] + b[c];
    out[(size_t)e * 64 + c] = f2bf(siluf_(y));
}

// ---------------- rotate: wigner @ concat(nf[snd],nf[rcv]); scale by x_edge; pack A1 (chunked) ----------------
__global__ __launch_bounds__(256) void k_rotate(const float* __restrict__ nf, const float* __restrict__ wig,
                                                const int* __restrict__ snd, const int* __restrict__ rcv,
                                                const u16* __restrict__ xe, u16* __restrict__ A1, int e0) {
    __shared__ float wl[2][475];
    int tid = threadIdx.x;
    for (int i = tid; i < 950; i += 256) {
        int ee = e0 + blockIdx.x * 2 + (i / 475);
        wl[i / 475][i % 475] = wig[(size_t)ee * 475 + (i % 475)];
    }
    __syncthreads();
    int le = tid >> 7, c = tid & 127;
    int el = blockIdx.x * 2 + le;       // chunk-local
    int e = e0 + el;                    // global
    int nd = (c < 64) ? snd[e] : rcv[e];
    int cc = c & 63;
    float msg[25];
#pragma unroll
    for (int k = 0; k < 25; k++) msg[k] = nf[(size_t)nd * 1600 + k * 64 + cc];
    const float* w = wl[le];
    size_t ebase = (size_t)el * 2432;
    size_t xbase = (size_t)el * 1536;
#pragma unroll
    for (int m = 0; m < 19; m++) {
        float r = 0.f;
#pragma unroll
        for (int k = 0; k < 25; k++) r += w[m * 25 + k] * msg[k];
        int a1c, xc;
        if (m < 5)       { a1c = m * 128;               xc = m * 128; }
        else if (m < 9)  { a1c = 640 + (m - 5) * 128;   xc = 640 + (m - 5) * 128; }
        else if (m < 13) { a1c = 1152 + (m - 9) * 128;  xc = 640 + (m - 9) * 128; }
        else if (m < 16) { a1c = 1664 + (m - 13) * 128; xc = 1152 + (m - 13) * 128; }
        else             { a1c = 2048 + (m - 16) * 128; xc = 1152 + (m - 16) * 128; }
        float sc = bf2f(xe[xbase + xc + c]);
        A1[ebase + a1c + c] = f2bf(r * sc);
    }
}

// ---------------- attention logits + segment max ----------------
__global__ __launch_bounds__(256) void k_logits(const u16* __restrict__ Y0, const int* __restrict__ rcv,
                                                const float* __restrict__ g, const float* __restrict__ b,
                                                const float* __restrict__ adot,
                                                float* __restrict__ logits, u32* __restrict__ nmax) {
    int e = blockIdx.x;
    int tid = threadIdx.x;
    int h = tid >> 5, c = tid & 31;
    float x = bf2f(Y0[(size_t)e * 640 + 320 + h * 32 + c]);
    float s = x, s2 = x * x;
#pragma unroll
    for (int o = 16; o; o >>= 1) { s += __shfl_xor(s, o); s2 += __shfl_xor(s2, o); }
    float mu = s * (1.f / 32.f);
    float var = s2 * (1.f / 32.f) - mu * mu;
    float rs = rsqrtf(var + 1e-5f);
    float a = (x - mu) * rs * g[c] + b[c];
    float f = 0.6f * a + 0.4f * a * (2.f * sigmoidf_(a) - 1.f);
    float l = f * adot[h * 32 + c];
#pragma unroll
    for (int o = 16; o; o >>= 1) l += __shfl_xor(l, o);
    if (c == 0) {
        logits[e * 8 + h] = l;
        atomicMax(&nmax[rcv[e] * 8 + h], encf(l));
    }
}

__global__ void k_expsum(const float* __restrict__ logits, const int* __restrict__ rcv,
                         const u32* __restrict__ nmax, float* __restrict__ ealpha, float* __restrict__ nsum) {
    int idx = blockIdx.x * 256 + threadIdx.x;
    if (idx >= E_EDGES * 8) return;
    int e = idx >> 3, h = idx & 7;
    int r = rcv[e];
    float amax = decf(nmax[r * 8 + h]);
    if (!(amax > -1e38f && amax < 1e38f)) amax = 0.f;
    float v = expf(logits[idx] - amax);
    ealpha[idx] = v;
    atomicAdd(&nsum[r * 8 + h], v);
}

// ---------------- grid round-trip via MFMA (replaces scalar k_grid) ----------------
// Per block: 2 edges -> 128 (e,c) rows. T1 = X(128x32) @ tgP^T -> silu -> T2 = T1(128x128) @ fgP^T.
// Writes A2[e][m*64+c]: m=0 gate row + m=1..18 from T2.
#define GR_XS_STR 40
#define GR_T1_STR 136
__global__ __launch_bounds__(256) void k_grid_mfma(
    const u16* __restrict__ Y0, const u16* __restrict__ Y1, const u16* __restrict__ Y2,
    const u16* __restrict__ tgP, const u16* __restrict__ fgP, u16* __restrict__ A2) {
    __shared__ u16 Xs[128 * GR_XS_STR];
    __shared__ u16 T1s[128 * GR_T1_STR];
    int tid = threadIdx.x;
    int e0 = blockIdx.x * 2;
    // zero T1s pad cols 112..127 (16B aligned: 272*row + 224 + tid16)
    {
        int row = tid >> 1;
        uint4 z = {0, 0, 0, 0};
        *(uint4*)(&T1s[row * GR_T1_STR + 112 + (tid & 1) * 8]) = z;
    }
    // stage Xs[row][m], row=(le*64+c), m 0..31 (>=19 zero)
    {
        int row = tid & 127;
        int half = tid >> 7;
        int e = e0 + (row >> 6);
        int c = row & 63;
#pragma unroll
        for (int j = 0; j < 16; j++) {
            int m = half * 16 + j;
            u16 v = 0;
            if (m < 5)       v = Y0[(size_t)e * 640 + m * 64 + c];
            else if (m < 13) v = Y1[(size_t)e * 512 + (m - 5) * 64 + c];
            else if (m < 19) v = Y2[(size_t)e * 384 + (m - 13) * 64 + c];
            Xs[row * GR_XS_STR + m] = v;
        }
    }
    __syncthreads();
    int wave = tid >> 6, lane = tid & 63;
    int wr = wave * 32;
    int ln = lane & 15, q = lane >> 4;
    // GEMM1: single K-step (K=32)
    short8 a0 = *(const short8*)(&Xs[(wr + ln) * GR_XS_STR + q * 8]);
    short8 a1 = *(const short8*)(&Xs[(wr + 16 + ln) * GR_XS_STR + q * 8]);
    floatx4 acc1[2][7];
#pragma unroll
    for (int pt = 0; pt < 7; pt++) {
        short8 b = *(const short8*)(&tgP[(size_t)(pt * 16 + ln) * 32 + q * 8]);
        acc1[0][pt] = __builtin_amdgcn_mfma_f32_16x16x32_bf16(a0, b, floatx4{0.f, 0.f, 0.f, 0.f}, 0, 0, 0);
        acc1[1][pt] = __builtin_amdgcn_mfma_f32_16x16x32_bf16(a1, b, floatx4{0.f, 0.f, 0.f, 0.f}, 0, 0, 0);
    }
    // silu -> T1s (C layout: col=pt*16+ln, row=wr+rt*16+q*4+r)
#pragma unroll
    for (int rt = 0; rt < 2; rt++)
#pragma unroll
        for (int pt = 0; pt < 7; pt++)
#pragma unroll
            for (int r = 0; r < 4; r++) {
                int row = wr + rt * 16 + q * 4 + r;
                T1s[row * GR_T1_STR + pt * 16 + ln] = f2bf(siluf_(acc1[rt][pt][r]));
            }
    __syncthreads();
    // GEMM2: K=128 (4 steps)
    floatx4 acc2[2][2];
    acc2[0][0] = floatx4{0.f, 0.f, 0.f, 0.f}; acc2[0][1] = floatx4{0.f, 0.f, 0.f, 0.f};
    acc2[1][0] = floatx4{0.f, 0.f, 0.f, 0.f}; acc2[1][1] = floatx4{0.f, 0.f, 0.f, 0.f};
#pragma unroll
    for (int ks = 0; ks < 4; ks++) {
        short8 c0 = *(const short8*)(&T1s[(wr + ln) * GR_T1_STR + ks * 32 + q * 8]);
        short8 c1 = *(const short8*)(&T1s[(wr + 16 + ln) * GR_T1_STR + ks * 32 + q * 8]);
#pragma unroll
        for (int ct = 0; ct < 2; ct++) {
            short8 b = *(const short8*)(&fgP[(size_t)(ct * 16 + ln) * 128 + ks * 32 + q * 8]);
            acc2[0][ct] = __builtin_amdgcn_mfma_f32_16x16x32_bf16(c0, b, acc2[0][ct], 0, 0, 0);
            acc2[1][ct] = __builtin_amdgcn_mfma_f32_16x16x32_bf16(c1, b, acc2[1][ct], 0, 0, 0);
        }
    }
    // T2 -> Xs (reuse; wave-local rows) as [row][m']
#pragma unroll
    for (int rt = 0; rt < 2; rt++)
#pragma unroll
        for (int ct = 0; ct < 2; ct++)
#pragma unroll
            for (int r = 0; r < 4; r++) {
                int row = wr + rt * 16 + q * 4 + r;
                Xs[row * GR_XS_STR + ct * 16 + ln] = f2bf(acc2[rt][ct][r]);
            }
    __syncthreads();
    // coalesced out: m=1..18 from Xs
    for (int i = tid; i < 128 * 18; i += 256) {
        int m = (i >> 7) + 1;
        int row = i & 127;
        int e = e0 + (row >> 6), c = row & 63;
        A2[(size_t)e * 1216 + m * 64 + c] = Xs[row * GR_XS_STR + m];
    }
    // m=0 gate row
    if (tid < 128) {
        int e = e0 + (tid >> 6), c = tid & 63;
        float gate = bf2f(Y0[(size_t)e * 640 + 576 + c]);
        A2[(size_t)e * 1216 + c] = f2bf(siluf_(gate));
    }
}

// ---------------- attention scale + wigner^T + segment-sum into node (chunked) ----------------
__global__ __launch_bounds__(256) void k_scatter(const u16* __restrict__ Z0, const u16* __restrict__ Z1,
                                                 const u16* __restrict__ Z2, const float* __restrict__ wig,
                                                 const float* __restrict__ ealpha, const float* __restrict__ nsum,
                                                 const int* __restrict__ rcv, float* __restrict__ node, int e0) {
    __shared__ float wl[2][475];
    int tid = threadIdx.x;
    for (int i = tid; i < 950; i += 256) {
        int ee = e0 + blockIdx.x * 2 + (i / 475);
        wl[i / 475][i % 475] = wig[(size_t)ee * 475 + (i % 475)];
    }
    __syncthreads();
    int le = tid >> 7, c = tid & 127;
    int el = blockIdx.x * 2 + le;
    int e = e0 + el;
    int r = rcv[e];
    int h = c >> 4;
    float al = ealpha[e * 8 + h] / (nsum[r * 8 + h] + 1e-16f);
    float s[19];
#pragma unroll
    for (int m = 0; m < 19; m++) {
        float v;
        if (m < 5)       v = bf2f(Z0[(size_t)el * 640 + m * 128 + c]);
        else if (m < 13) v = bf2f(Z1[(size_t)el * 1024 + (m - 5) * 128 + c]);
        else             v = bf2f(Z2[(size_t)el * 768 + (m - 13) * 128 + c]);
        s[m] = v * al;
    }
    const float* w = wl[le];
    float* nb = node + (size_t)r * 3200 + c;
#pragma unroll
    for (int k = 0; k < 25; k++) {
        float acc = 0.f;
#pragma unroll
        for (int m = 0; m < 19; m++) acc += w[m * 25 + k] * s[m];
        atomicAdd(&nb[k * 128], acc);
    }
}

// ---------------- final projection (f32 node, f32 weights, f32 out) ----------------
__global__ void k_proj(const float* __restrict__ node, const float* __restrict__ pw,
                       const float* __restrict__ pb, float* __restrict__ out) {
    int n = blockIdx.x;
    int tid = threadIdx.x;
    int d = tid & 63, kk = tid >> 6;
    for (int k = kk; k < 25; k += 4) {
        int l = (int)sqrtf((float)k + 0.5f);
        const float* nr = node + (size_t)n * 3200 + k * 128;
        const float* w = pw + (size_t)l * 8192 + d;
        float acc = 0.f;
#pragma unroll 8
        for (int c = 0; c < 128; c++) acc += nr[c] * w[c * 64];
        if (k == 0) acc += pb[d];
        out[(size_t)n * 1600 + k * 64 + d] = acc;
    }
}

extern "C" void kernel_launch(void* const* d_in, const int* in_sizes, int n_in,
                              void* d_out, int out_size, void* d_ws, size_t ws_size,
                              hipStream_t stream) {
    const float* nf      = (const float*)d_in[0];
    const int* species   = (const int*)d_in[1];
    const float* dist    = (const float*)d_in[2];
    const int* snd       = (const int*)d_in[3];
    const int* rcv       = (const int*)d_in[4];
    const float* wig     = (const float*)d_in[5];
    const float* semb    = (const float*)d_in[6];
    const float* remb    = (const float*)d_in[7];
    const float* rad_w1  = (const float*)d_in[8];
    const float* rad_b1  = (const float*)d_in[9];
    const float* rad_g1  = (const float*)d_in[10];
    const float* rad_be1 = (const float*)d_in[11];
    const float* rad_w2  = (const float*)d_in[12];
    const float* rad_b2  = (const float*)d_in[13];
    const float* rad_g2  = (const float*)d_in[14];
    const float* rad_be2 = (const float*)d_in[15];
    const float* rad_w3  = (const float*)d_in[16];
    const float* rad_b3  = (const float*)d_in[17];
    const float* c1_w0   = (const float*)d_in[18];
    const float* c1_b0   = (const float*)d_in[19];
    const float* c1_wm1  = (const float*)d_in[20];
    const float* c1_wm2  = (const float*)d_in[21];
    const float* aln_g   = (const float*)d_in[22];
    const float* aln_b   = (const float*)d_in[23];
    const float* adot    = (const float*)d_in[24];
    const float* to_grid = (const float*)d_in[25];
    const float* from_grid=(const float*)d_in[26];
    const float* c2_w0   = (const float*)d_in[27];
    const float* c2_b0   = (const float*)d_in[28];
    const float* c2_wm1  = (const float*)d_in[29];
    const float* c2_wm2  = (const float*)d_in[30];
    const float* proj_w  = (const float*)d_in[31];
    const float* proj_b  = (const float*)d_in[32];

    char* ws = (char*)d_ws;
    size_t off = 0;
    auto take = [&](size_t bytes) -> char* {
        char* p = ws + off;
        off += (bytes + 255) & ~(size_t)255;
        return p;
    };
    // fixed section
    u16* w_rad1T  = (u16*)take(64 * 192 * 2);
    u16* w_rad2T  = (u16*)take(64 * 64 * 2);
    u16* w_rad3T  = (u16*)take(1536 * 64 * 2);
    u16* w_c1w0T  = (u16*)take(640 * 640 * 2);
    u16* w_c1m1T  = (u16*)take((size_t)512 * 1024 * 2);
    u16* w_c1m2T  = (u16*)take((size_t)384 * 768 * 2);
    u16* w_c2w0T  = (u16*)take((size_t)640 * 320 * 2);
    u16* w_c2m1T  = (u16*)take((size_t)1024 * 512 * 2);
    u16* w_c2m2T  = (u16*)take((size_t)768 * 384 * 2);
    u16* w_tgP    = (u16*)take(112 * 32 * 2);
    u16* w_fgP    = (u16*)take(32 * 128 * 2);
    float* logits = (float*)take((size_t)E_EDGES * 8 * 4);
    float* ealpha = (float*)take((size_t)E_EDGES * 8 * 4);
    u32* nmax     = (u32*)take((size_t)N_NODES_C * 8 * 4);
    float* nsum   = (float*)take((size_t)N_NODES_C * 8 * 4);
    float* node   = (float*)take((size_t)N_NODES_C * 3200 * 4);
    u16* a_h2     = (u16*)take((size_t)E_EDGES * 64 * 2);
    // arena — aliased by phase
    char* arena   = take(173015040);
    if (off > ws_size) {  // diagnostic: paint output so the failure mode is identifiable
        k_diag<<<(out_size + 255) / 256, 256, 0, stream>>>((float*)d_out, out_size);
        return;
    }

    u16* a_ee   = (u16*)(arena + 0);           // radial phase
    u16* a_ypre = (u16*)(arena + 9437184);
    u16* a_h1   = (u16*)(arena + 12582912);
    u16* a_xe   = (u16*)(arena + 0);           // per-chunk (EC,1536); radial staging dead
    u16* a_A1   = (u16*)(arena + 37748736);    // per-chunk (EC,2432)
    u16* a_Y0   = (u16*)(arena + 97517568);    // full (E,640)
    u16* a_Y1   = (u16*)(arena + 128974848);   // full (E,512)
    u16* a_Y2   = (u16*)(arena + 154140672);   // full (E,384) -> arena end
    u16* a_A2   = (u16*)(arena + 0);           // full (E,1216); xe/A1 dead
    u16* a_Z0   = (u16*)(arena + 59768832);    // per-chunk (EC,640)
    u16* a_Z1   = (u16*)(arena + 75497472);    // per-chunk (EC,1024)
    u16* a_Z2   = (u16*)(arena + 100663296);   // per-chunk (EC,768); overlaps dead Y0 region

    // ---- weight prep ----
    k_transpose<<<48, 256, 0, stream>>>(rad_w1, w_rad1T, 192, 64);
    k_transpose<<<16, 256, 0, stream>>>(rad_w2, w_rad2T, 64, 64);
    k_transpose<<<384, 256, 0, stream>>>(rad_w3, w_rad3T, 64, 1536);
    k_transpose<<<1600, 256, 0, stream>>>(c1_w0, w_c1w0T, 640, 640);
    k_transpose<<<800, 256, 0, stream>>>(c2_w0, w_c2w0T, 320, 640);
    k_combine<<<2048, 256, 0, stream>>>(c1_wm1, w_c1m1T, 512, 256);
    k_combine<<<1152, 256, 0, stream>>>(c1_wm2, w_c1m2T, 384, 192);
    k_combine<<<2048, 256, 0, stream>>>(c2_wm1, w_c2m1T, 256, 512);
    k_combine<<<1152, 256, 0, stream>>>(c2_wm2, w_c2m2T, 192, 384);
    k_packgrid<<<30, 256, 0, stream>>>(to_grid, from_grid, w_tgP, w_fgP);
    k_init<<<128, 256, 0, stream>>>(nmax, nsum, N_NODES_C * 8);
    hipMemsetAsync(node, 0, (size_t)N_NODES_C * 3200 * 4, stream);

    // ---- radial MLP (full E) ----
    k_ee<<<(E_EDGES * 192 + 255) / 256, 256, 0, stream>>>(dist, species, snd, rcv, semb, remb, a_ee);
    k_gemm<<<dim3(192, 1), 256, 0, stream>>>(a_ee, 192, w_rad1T, 192, a_ypre, 64, 64, 192, rad_b1);
    k_ln_silu<<<6144, 256, 0, stream>>>(a_ypre, a_h1, rad_g1, rad_be1);
    k_gemm<<<dim3(192, 1), 256, 0, stream>>>(a_h1, 64, w_rad2T, 64, a_ypre, 64, 64, 64, rad_b2);
    k_ln_silu<<<6144, 256, 0, stream>>>(a_ypre, a_h2, rad_g2, rad_be2);

    // ---- chunked: x_edge gemm -> rotate -> conv1 ----
    for (int c = 0; c < 2; c++) {
        int e0 = c * EC;
        k_gemm<<<dim3(96, 12), 256, 0, stream>>>(a_h2 + (size_t)e0 * 64, 64, w_rad3T, 64,
                                                 a_xe, 1536, 1536, 64, rad_b3);
        k_rotate<<<EC / 2, 256, 0, stream>>>(nf, wig, snd, rcv, a_xe, a_A1, e0);
        k_gemm<<<dim3(96, 5), 256, 0, stream>>>(a_A1, 2432, w_c1w0T, 640,
                                                a_Y0 + (size_t)e0 * 640, 640, 640, 640, c1_b0);
        k_gemm<<<dim3(96, 4), 256, 0, stream>>>(a_A1 + 640, 2432, w_c1m1T, 1024,
                                                a_Y1 + (size_t)e0 * 512, 512, 512, 1024, nullptr);
        k_gemm<<<dim3(96, 3), 256, 0, stream>>>(a_A1 + 1664, 2432, w_c1m2T, 768,
                                                a_Y2 + (size_t)e0 * 384, 384, 384, 768, nullptr);
    }

    // ---- attention softmax pieces ----
    k_logits<<<E_EDGES, 256, 0, stream>>>(a_Y0, rcv, aln_g, aln_b, adot, logits, nmax);
    k_expsum<<<(E_EDGES * 8 + 255) / 256, 256, 0, stream>>>(logits, rcv, nmax, ealpha, nsum);

    // ---- grid nonlinearity -> packed A2 (full E, MFMA) ----
    k_grid_mfma<<<E_EDGES / 2, 256, 0, stream>>>(a_Y0, a_Y1, a_Y2, w_tgP, w_fgP, a_A2);

    // ---- chunked: conv2 -> scatter ----
    for (int c = 0; c < 2; c++) {
        int e0 = c * EC;
        k_gemm<<<dim3(96, 5), 256, 0, stream>>>(a_A2 + (size_t)e0 * 1216, 1216, w_c2w0T, 320,
                                                a_Z0, 640, 640, 320, c2_b0);
        k_gemm<<<dim3(96, 8), 256, 0, stream>>>(a_A2 + (size_t)e0 * 1216 + 320, 1216, w_c2m1T, 512,
                                                a_Z1, 1024, 1024, 512, nullptr);
        k_gemm<<<dim3(96, 6), 256, 0, stream>>>(a_A2 + (size_t)e0 * 1216 + 832, 1216, w_c2m2T, 384,
                                                a_Z2, 768, 768, 384, nullptr);
        k_scatter<<<EC / 2, 256, 0, stream>>>(a_Z0, a_Z1, a_Z2, wig, ealpha, nsum, rcv, node, e0);
    }

    // ---- output projection ----
    k_proj<<<N_NODES_C, 256, 0, stream>>>(node, proj_w, proj_b, (float*)d_out);
}

// Round 7
// 1301.441 us; speedup vs baseline: 1.1241x; 1.0235x over previous
//
#include <hip/hip_runtime.h>

typedef unsigned short u16;
typedef unsigned int u32;
typedef __attribute__((ext_vector_type(8))) short short8;
typedef __attribute__((ext_vector_type(4))) float floatx4;

#define E_EDGES 24576
#define EC 12288            // edge chunk
#define N_NODES_C 4096

__device__ __forceinline__ float bf2f(u16 u) {
    union { u32 i; float f; } v; v.i = ((u32)u) << 16; return v.f;
}
__device__ __forceinline__ u16 f2bf(float f) {
    union { float f; u32 i; } v; v.f = f;
    u32 x = v.i;
    u32 r = (x + 0x7fffu + ((x >> 16) & 1u)) >> 16;
    return (u16)r;
}
__device__ __forceinline__ u32 encf(float f) {
    union { float f; u32 i; } v; v.f = f;
    return (v.i & 0x80000000u) ? ~v.i : (v.i | 0x80000000u);
}
__device__ __forceinline__ float decf(u32 u) {
    union { u32 i; float f; } v;
    v.i = (u & 0x80000000u) ? (u ^ 0x80000000u) : ~u;
    return v.f;
}
// fast transcendentals: v_exp_f32 + v_rcp_f32 (libm expf/div without fast-math is ~30+ instrs)
__device__ __forceinline__ float sigmoidf_(float x) { return __fdividef(1.f, 1.f + __expf(-x)); }
__device__ __forceinline__ float siluf_(float x) { return x * __fdividef(1.f, 1.f + __expf(-x)); }

// async global->LDS, 16B per lane; LDS dest must be wave-uniform base + lane*16
__device__ __forceinline__ void gld16(const u16* g, u16* l) {
    __builtin_amdgcn_global_load_lds((const __attribute__((address_space(1))) unsigned int*)g,
                                     (__attribute__((address_space(3))) unsigned int*)l, 16, 0, 0);
}

// diagnostic: ws too small -> paint output with 1000 (f32)
__global__ void k_diag(float* __restrict__ out, int n) {
    int i = blockIdx.x * 256 + threadIdx.x;
    if (i < n) out[i] = 1000.0f;
}

// ---------------- weight prep (f32 src -> bf16 transposed) ----------------
__global__ void k_transpose(const float* __restrict__ src, u16* __restrict__ dst, int K, int N) {
    int idx = blockIdx.x * 256 + threadIdx.x;
    if (idx >= K * N) return;
    int k = idx / N, n = idx % N;
    dst[n * K + k] = f2bf(src[idx]);
}
// combined complex weight, pre-transposed. src (K, 2H) f32: wa=cols[0:H), wb=cols[H:2H).
// dst (2H, 2K) bf16: dst[n][k] = k<K ? src[k][n] : (n<H ? -src[k-K][H+n] : src[k-K][n-H])
__global__ void k_combine(const float* __restrict__ src, u16* __restrict__ dst, int K, int H) {
    int total = 4 * K * H;
    int idx = blockIdx.x * 256 + threadIdx.x;
    if (idx >= total) return;
    int n = idx / (2 * K), k = idx % (2 * K);
    float v;
    if (k < K) v = src[k * 2 * H + n];
    else {
        int kk = k - K;
        if (n < H) v = -src[kk * 2 * H + H + n];
        else       v = src[kk * 2 * H + (n - H)];
    }
    dst[idx] = f2bf(v);
}

// pack to_grid (100,19) -> tgP[112][32] bf16; pack from_grid (19,100) -> fgP[32][128] bf16
__global__ void k_packgrid(const float* __restrict__ tg, const float* __restrict__ fg,
                           u16* __restrict__ tgP, u16* __restrict__ fgP) {
    int idx = blockIdx.x * 256 + threadIdx.x;
    if (idx < 112 * 32) {
        int p = idx >> 5, m = idx & 31;
        tgP[idx] = (p < 100 && m < 19) ? f2bf(tg[p * 19 + m]) : (u16)0;
    }
    int j = idx - 112 * 32;
    if (j >= 0 && j < 32 * 128) {
        int m = j >> 7, k = j & 127;
        fgP[j] = (m < 19 && k < 100) ? f2bf(fg[m * 100 + k]) : (u16)0;
    }
}

__global__ void k_init(u32* __restrict__ nmax, float* __restrict__ nsum, int n) {
    int idx = blockIdx.x * 256 + threadIdx.x;
    if (idx < n) { nmax[idx] = 0x007FFFFFu; /* enc(-inf) */ nsum[idx] = 0.f; }
}

// ---------------- edge embeddings (f32 in -> bf16 A) ----------------
__global__ void k_ee(const float* __restrict__ dist, const int* __restrict__ species,
                     const int* __restrict__ snd, const int* __restrict__ rcv,
                     const float* __restrict__ semb, const float* __restrict__ remb,
                     u16* __restrict__ ee) {
    int idx = blockIdx.x * 256 + threadIdx.x;
    if (idx >= E_EDGES * 192) return;
    int e = idx / 192, c = idx % 192;
    float v;
    if (c < 64)       v = dist[e * 64 + c];
    else if (c < 128) v = semb[species[snd[e]] * 64 + (c - 64)];
    else              v = remb[species[rcv[e]] * 64 + (c - 128)];
    ee[idx] = f2bf(v);
}

// ---------------- GEMM (m97 structure): A (M,K) bf16 rm, BT (N,K) bf16 rm, C (M,N) bf16 ----------------
// global_load_lds staging, unpadded 64B rows. M%128==0, K%32==0; N guarded.
// NOTE: explicit s_waitcnt vmcnt(0) before the barrier — the async LDS-DMA must be drained
// before any wave crosses s_barrier (round-6 post-timing divergence = this race).
__global__ __launch_bounds__(256) void k_gemm(
    const u16* __restrict__ A, int lda,
    const u16* __restrict__ BT, int ldb,
    u16* __restrict__ C, int ldc,
    int N, int K,
    const float* __restrict__ bias) {
    __shared__ u16 As[128 * 32];
    __shared__ u16 Bs[128 * 32];
    int tid = threadIdx.x;
    int bm0 = blockIdx.x * 128;
    int bn0 = blockIdx.y * 128;
    int wave = tid >> 6, lane = tid & 63;
    int wm = (wave >> 1) * 64, wn = (wave & 1) * 64;
    int lrow = lane & 15, lk = (lane >> 4) * 8;

    // staging geometry: wave w covers rows w*16 + (lane>>2), 16B chunk (lane&3)
    int srow = (wave << 4) + (lane >> 2);        // 0..63
    int schunk = (lane & 3) << 3;                // u16 offset 0/8/16/24
    const u16* Arow0 = A + (size_t)(bm0 + srow) * lda + schunk;
    const u16* Arow1 = A + (size_t)(bm0 + srow + 64) * lda + schunk;
    int n0 = bn0 + srow;      if (n0 >= N) n0 = N - 1;
    int n1 = bn0 + srow + 64; if (n1 >= N) n1 = N - 1;
    const u16* Brow0 = BT + (size_t)n0 * ldb + schunk;
    const u16* Brow1 = BT + (size_t)n1 * ldb + schunk;
    u16* lA0 = &As[srow * 32 + schunk];
    u16* lA1 = &As[(srow + 64) * 32 + schunk];
    u16* lB0 = &Bs[srow * 32 + schunk];
    u16* lB1 = &Bs[(srow + 64) * 32 + schunk];

    floatx4 acc[4][4];
#pragma unroll
    for (int i = 0; i < 4; i++)
#pragma unroll
        for (int j = 0; j < 4; j++) acc[i][j] = floatx4{0.f, 0.f, 0.f, 0.f};

    for (int k0 = 0; k0 < K; k0 += 32) {
        gld16(Arow0 + k0, lA0);
        gld16(Arow1 + k0, lA1);
        gld16(Brow0 + k0, lB0);
        gld16(Brow1 + k0, lB1);
        asm volatile("s_waitcnt vmcnt(0)" ::: "memory");
        __syncthreads();
        short8 a[4], b[4];
#pragma unroll
        for (int i = 0; i < 4; i++) a[i] = *(const short8*)(&As[(wm + i * 16 + lrow) * 32 + lk]);
#pragma unroll
        for (int j = 0; j < 4; j++) b[j] = *(const short8*)(&Bs[(wn + j * 16 + lrow) * 32 + lk]);
#pragma unroll
        for (int i = 0; i < 4; i++)
#pragma unroll
            for (int j = 0; j < 4; j++)
                acc[i][j] = __builtin_amdgcn_mfma_f32_16x16x32_bf16(a[i], b[j], acc[i][j], 0, 0, 0);
        __syncthreads();
    }

    int q = lane >> 4;
#pragma unroll
    for (int i = 0; i < 4; i++) {
#pragma unroll
        for (int j = 0; j < 4; j++) {
            int col = bn0 + wn + j * 16 + lrow;
            if (col < N) {
                float bv = bias ? bias[col] : 0.f;
#pragma unroll
                for (int r = 0; r < 4; r++) {
                    int row = bm0 + wm + i * 16 + q * 4 + r;
                    C[(size_t)row * ldc + col] = f2bf(acc[i][j][r] + bv);
                }
            }
        }
    }
}

// ---------------- LayerNorm(64) + SiLU (bf16 io, f32 params) ----------------
__global__ __launch_bounds__(256) void k_ln_silu(const u16* __restrict__ in, u16* __restrict__ out,
                                                 const float* __restrict__ g, const float* __restrict__ b) {
    int tid = threadIdx.x;
    int e = blockIdx.x * 4 + (tid >> 6);
    int c = tid & 63;
    float x = bf2f(in[(size_t)e * 64 + c]);
    float s = x, s2 = x * x;
#pragma unroll
    for (int o = 32; o; o >>= 1) { s += __shfl_xor(s, o); s2 += __shfl_xor(s2, o); }
    float mu = s * (1.f / 64.f);
    float var = s2 * (1.f / 64.f) - mu * mu;
    float rs = rsqrtf(var + 1e-5f);
    float y = (x - mu) * rs * g[c] + b[c];
    out[(size_t)e * 64 + c] = f2bf(siluf_(y));
}

// ---------------- rotate: wigner @ concat(nf[snd],nf[rcv]); scale by x_edge; pack A1 (chunked) ----------------
__global__ __launch_bounds__(256) void k_rotate(const float* __restrict__ nf, const float* __restrict__ wig,
                                                const int* __restrict__ snd, const int* __restrict__ rcv,
                                                const u16* __restrict__ xe, u16* __restrict__ A1, int e0) {
    __shared__ float wl[2][475];
    int tid = threadIdx.x;
    for (int i = tid; i < 950; i += 256) {
        int ee = e0 + blockIdx.x * 2 + (i / 475);
        wl[i / 475][i % 475] = wig[(size_t)ee * 475 + (i % 475)];
    }
    __syncthreads();
    int le = tid >> 7, c = tid & 127;
    int el = blockIdx.x * 2 + le;       // chunk-local
    int e = e0 + el;                    // global
    int nd = (c < 64) ? snd[e] : rcv[e];
    int cc = c & 63;
    float msg[25];
#pragma unroll
    for (int k = 0; k < 25; k++) msg[k] = nf[(size_t)nd * 1600 + k * 64 + cc];
    const float* w = wl[le];
    size_t ebase = (size_t)el * 2432;
    size_t xbase = (size_t)el * 1536;
#pragma unroll
    for (int m = 0; m < 19; m++) {
        float r = 0.f;
#pragma unroll
        for (int k = 0; k < 25; k++) r += w[m * 25 + k] * msg[k];
        int a1c, xc;
        if (m < 5)       { a1c = m * 128;               xc = m * 128; }
        else if (m < 9)  { a1c = 640 + (m - 5) * 128;   xc = 640 + (m - 5) * 128; }
        else if (m < 13) { a1c = 1152 + (m - 9) * 128;  xc = 640 + (m - 9) * 128; }
        else if (m < 16) { a1c = 1664 + (m - 13) * 128; xc = 1152 + (m - 13) * 128; }
        else             { a1c = 2048 + (m - 16) * 128; xc = 1152 + (m - 16) * 128; }
        float sc = bf2f(xe[xbase + xc + c]);
        A1[ebase + a1c + c] = f2bf(r * sc);
    }
}

// ---------------- attention logits + segment max ----------------
__global__ __launch_bounds__(256) void k_logits(const u16* __restrict__ Y0, const int* __restrict__ rcv,
                                                const float* __restrict__ g, const float* __restrict__ b,
                                                const float* __restrict__ adot,
                                                float* __restrict__ logits, u32* __restrict__ nmax) {
    int e = blockIdx.x;
    int tid = threadIdx.x;
    int h = tid >> 5, c = tid & 31;
    float x = bf2f(Y0[(size_t)e * 640 + 320 + h * 32 + c]);
    float s = x, s2 = x * x;
#pragma unroll
    for (int o = 16; o; o >>= 1) { s += __shfl_xor(s, o); s2 += __shfl_xor(s2, o); }
    float mu = s * (1.f / 32.f);
    float var = s2 * (1.f / 32.f) - mu * mu;
    float rs = rsqrtf(var + 1e-5f);
    float a = (x - mu) * rs * g[c] + b[c];
    float f = 0.6f * a + 0.4f * a * (2.f * sigmoidf_(a) - 1.f);
    float l = f * adot[h * 32 + c];
#pragma unroll
    for (int o = 16; o; o >>= 1) l += __shfl_xor(l, o);
    if (c == 0) {
        logits[e * 8 + h] = l;
        atomicMax(&nmax[rcv[e] * 8 + h], encf(l));
    }
}

__global__ void k_expsum(const float* __restrict__ logits, const int* __restrict__ rcv,
                         const u32* __restrict__ nmax, float* __restrict__ ealpha, float* __restrict__ nsum) {
    int idx = blockIdx.x * 256 + threadIdx.x;
    if (idx >= E_EDGES * 8) return;
    int e = idx >> 3, h = idx & 7;
    int r = rcv[e];
    float amax = decf(nmax[r * 8 + h]);
    if (!(amax > -1e38f && amax < 1e38f)) amax = 0.f;
    float v = __expf(logits[idx] - amax);
    ealpha[idx] = v;
    atomicAdd(&nsum[r * 8 + h], v);
}

// ---------------- grid round-trip via MFMA ----------------
// Per block: 2 edges -> 128 (e,c) rows. T1 = X(128x32) @ tgP^T -> silu -> T2 = T1(128x128) @ fgP^T.
#define GR_XS_STR 40
#define GR_T1_STR 136
__global__ __launch_bounds__(256) void k_grid_mfma(
    const u16* __restrict__ Y0, const u16* __restrict__ Y1, const u16* __restrict__ Y2,
    const u16* __restrict__ tgP, const u16* __restrict__ fgP, u16* __restrict__ A2) {
    __shared__ u16 Xs[128 * GR_XS_STR];
    __shared__ u16 T1s[128 * GR_T1_STR];
    int tid = threadIdx.x;
    int e0 = blockIdx.x * 2;
    // zero T1s pad cols 112..127
    {
        int row = tid >> 1;
        uint4 z = {0, 0, 0, 0};
        *(uint4*)(&T1s[row * GR_T1_STR + 112 + (tid & 1) * 8]) = z;
    }
    // stage Xs[row][m], row=(le*64+c), m 0..31 (>=19 zero)
    {
        int row = tid & 127;
        int half = tid >> 7;
        int e = e0 + (row >> 6);
        int c = row & 63;
#pragma unroll
        for (int j = 0; j < 16; j++) {
            int m = half * 16 + j;
            u16 v = 0;
            if (m < 5)       v = Y0[(size_t)e * 640 + m * 64 + c];
            else if (m < 13) v = Y1[(size_t)e * 512 + (m - 5) * 64 + c];
            else if (m < 19) v = Y2[(size_t)e * 384 + (m - 13) * 64 + c];
            Xs[row * GR_XS_STR + m] = v;
        }
    }
    __syncthreads();
    int wave = tid >> 6, lane = tid & 63;
    int wr = wave * 32;
    int ln = lane & 15, q = lane >> 4;
    // GEMM1: single K-step (K=32)
    short8 a0 = *(const short8*)(&Xs[(wr + ln) * GR_XS_STR + q * 8]);
    short8 a1 = *(const short8*)(&Xs[(wr + 16 + ln) * GR_XS_STR + q * 8]);
    floatx4 acc1[2][7];
#pragma unroll
    for (int pt = 0; pt < 7; pt++) {
        short8 b = *(const short8*)(&tgP[(size_t)(pt * 16 + ln) * 32 + q * 8]);
        acc1[0][pt] = __builtin_amdgcn_mfma_f32_16x16x32_bf16(a0, b, floatx4{0.f, 0.f, 0.f, 0.f}, 0, 0, 0);
        acc1[1][pt] = __builtin_amdgcn_mfma_f32_16x16x32_bf16(a1, b, floatx4{0.f, 0.f, 0.f, 0.f}, 0, 0, 0);
    }
    // silu -> T1s (skip pad cols >= 100: pt==6 && ln>=4)
#pragma unroll
    for (int rt = 0; rt < 2; rt++)
#pragma unroll
        for (int pt = 0; pt < 7; pt++) {
            bool pad = (pt == 6) && (ln >= 4);
#pragma unroll
            for (int r = 0; r < 4; r++) {
                int row = wr + rt * 16 + q * 4 + r;
                T1s[row * GR_T1_STR + pt * 16 + ln] = pad ? (u16)0 : f2bf(siluf_(acc1[rt][pt][r]));
            }
        }
    __syncthreads();
    // GEMM2: K=128 (4 steps)
    floatx4 acc2[2][2];
    acc2[0][0] = floatx4{0.f, 0.f, 0.f, 0.f}; acc2[0][1] = floatx4{0.f, 0.f, 0.f, 0.f};
    acc2[1][0] = floatx4{0.f, 0.f, 0.f, 0.f}; acc2[1][1] = floatx4{0.f, 0.f, 0.f, 0.f};
#pragma unroll
    for (int ks = 0; ks < 4; ks++) {
        short8 c0 = *(const short8*)(&T1s[(wr + ln) * GR_T1_STR + ks * 32 + q * 8]);
        short8 c1 = *(const short8*)(&T1s[(wr + 16 + ln) * GR_T1_STR + ks * 32 + q * 8]);
#pragma unroll
        for (int ct = 0; ct < 2; ct++) {
            short8 b = *(const short8*)(&fgP[(size_t)(ct * 16 + ln) * 128 + ks * 32 + q * 8]);
            acc2[0][ct] = __builtin_amdgcn_mfma_f32_16x16x32_bf16(c0, b, acc2[0][ct], 0, 0, 0);
            acc2[1][ct] = __builtin_amdgcn_mfma_f32_16x16x32_bf16(c1, b, acc2[1][ct], 0, 0, 0);
        }
    }
    // T2 -> Xs (reuse) as [row][m']
#pragma unroll
    for (int rt = 0; rt < 2; rt++)
#pragma unroll
        for (int ct = 0; ct < 2; ct++)
#pragma unroll
            for (int r = 0; r < 4; r++) {
                int row = wr + rt * 16 + q * 4 + r;
                Xs[row * GR_XS_STR + ct * 16 + ln] = f2bf(acc2[rt][ct][r]);
            }
    __syncthreads();
    // coalesced out: m=1..18 from Xs
    for (int i = tid; i < 128 * 18; i += 256) {
        int m = (i >> 7) + 1;
        int row = i & 127;
        int e = e0 + (row >> 6), c = row & 63;
        A2[(size_t)e * 1216 + m * 64 + c] = Xs[row * GR_XS_STR + m];
    }
    // m=0 gate row
    if (tid < 128) {
        int e = e0 + (tid >> 6), c = tid & 63;
        float gate = bf2f(Y0[(size_t)e * 640 + 576 + c]);
        A2[(size_t)e * 1216 + c] = f2bf(siluf_(gate));
    }
}

// ---------------- attention scale + wigner^T + segment-sum into node (chunked) ----------------
__global__ __launch_bounds__(256) void k_scatter(const u16* __restrict__ Z0, const u16* __restrict__ Z1,
                                                 const u16* __restrict__ Z2, const float* __restrict__ wig,
                                                 const float* __restrict__ ealpha, const float* __restrict__ nsum,
                                                 const int* __restrict__ rcv, float* __restrict__ node, int e0) {
    __shared__ float wl[2][475];
    int tid = threadIdx.x;
    for (int i = tid; i < 950; i += 256) {
        int ee = e0 + blockIdx.x * 2 + (i / 475);
        wl[i / 475][i % 475] = wig[(size_t)ee * 475 + (i % 475)];
    }
    __syncthreads();
    int le = tid >> 7, c = tid & 127;
    int el = blockIdx.x * 2 + le;
    int e = e0 + el;
    int r = rcv[e];
    int h = c >> 4;
    float al = ealpha[e * 8 + h] / (nsum[r * 8 + h] + 1e-16f);
    float s[19];
#pragma unroll
    for (int m = 0; m < 19; m++) {
        float v;
        if (m < 5)       v = bf2f(Z0[(size_t)el * 640 + m * 128 + c]);
        else if (m < 13) v = bf2f(Z1[(size_t)el * 1024 + (m - 5) * 128 + c]);
        else             v = bf2f(Z2[(size_t)el * 768 + (m - 13) * 128 + c]);
        s[m] = v * al;
    }
    const float* w = wl[le];
    float* nb = node + (size_t)r * 3200 + c;
#pragma unroll
    for (int k = 0; k < 25; k++) {
        float acc = 0.f;
#pragma unroll
        for (int m = 0; m < 19; m++) acc += w[m * 25 + k] * s[m];
        atomicAdd(&nb[k * 128], acc);
    }
}

// ---------------- final projection (f32 node, f32 weights, f32 out) ----------------
__global__ void k_proj(const float* __restrict__ node, const float* __restrict__ pw,
                       const float* __restrict__ pb, float* __restrict__ out) {
    int n = blockIdx.x;
    int tid = threadIdx.x;
    int d = tid & 63, kk = tid >> 6;
    for (int k = kk; k < 25; k += 4) {
        int l = (int)sqrtf((float)k + 0.5f);
        const float* nr = node + (size_t)n * 3200 + k * 128;
        const float* w = pw + (size_t)l * 8192 + d;
        float acc = 0.f;
#pragma unroll 8
        for (int c = 0; c < 128; c++) acc += nr[c] * w[c * 64];
        if (k == 0) acc += pb[d];
        out[(size_t)n * 1600 + k * 64 + d] = acc;
    }
}

extern "C" void kernel_launch(void* const* d_in, const int* in_sizes, int n_in,
                              void* d_out, int out_size, void* d_ws, size_t ws_size,
                              hipStream_t stream) {
    const float* nf      = (const float*)d_in[0];
    const int* species   = (const int*)d_in[1];
    const float* dist    = (const float*)d_in[2];
    const int* snd       = (const int*)d_in[3];
    const int* rcv       = (const int*)d_in[4];
    const float* wig     = (const float*)d_in[5];
    const float* semb    = (const float*)d_in[6];
    const float* remb    = (const float*)d_in[7];
    const float* rad_w1  = (const float*)d_in[8];
    const float* rad_b1  = (const float*)d_in[9];
    const float* rad_g1  = (const float*)d_in[10];
    const float* rad_be1 = (const float*)d_in[11];
    const float* rad_w2  = (const float*)d_in[12];
    const float* rad_b2  = (const float*)d_in[13];
    const float* rad_g2  = (const float*)d_in[14];
    const float* rad_be2 = (const float*)d_in[15];
    const float* rad_w3  = (const float*)d_in[16];
    const float* rad_b3  = (const float*)d_in[17];
    const float* c1_w0   = (const float*)d_in[18];
    const float* c1_b0   = (const float*)d_in[19];
    const float* c1_wm1  = (const float*)d_in[20];
    const float* c1_wm2  = (const float*)d_in[21];
    const float* aln_g   = (const float*)d_in[22];
    const float* aln_b   = (const float*)d_in[23];
    const float* adot    = (const float*)d_in[24];
    const float* to_grid = (const float*)d_in[25];
    const float* from_grid=(const float*)d_in[26];
    const float* c2_w0   = (const float*)d_in[27];
    const float* c2_b0   = (const float*)d_in[28];
    const float* c2_wm1  = (const float*)d_in[29];
    const float* c2_wm2  = (const float*)d_in[30];
    const float* proj_w  = (const float*)d_in[31];
    const float* proj_b  = (const float*)d_in[32];

    char* ws = (char*)d_ws;
    size_t off = 0;
    auto take = [&](size_t bytes) -> char* {
        char* p = ws + off;
        off += (bytes + 255) & ~(size_t)255;
        return p;
    };
    // fixed section
    u16* w_rad1T  = (u16*)take(64 * 192 * 2);
    u16* w_rad2T  = (u16*)take(64 * 64 * 2);
    u16* w_rad3T  = (u16*)take(1536 * 64 * 2);
    u16* w_c1w0T  = (u16*)take(640 * 640 * 2);
    u16* w_c1m1T  = (u16*)take((size_t)512 * 1024 * 2);
    u16* w_c1m2T  = (u16*)take((size_t)384 * 768 * 2);
    u16* w_c2w0T  = (u16*)take((size_t)640 * 320 * 2);
    u16* w_c2m1T  = (u16*)take((size_t)1024 * 512 * 2);
    u16* w_c2m2T  = (u16*)take((size_t)768 * 384 * 2);
    u16* w_tgP    = (u16*)take(112 * 32 * 2);
    u16* w_fgP    = (u16*)take(32 * 128 * 2);
    float* logits = (float*)take((size_t)E_EDGES * 8 * 4);
    float* ealpha = (float*)take((size_t)E_EDGES * 8 * 4);
    u32* nmax     = (u32*)take((size_t)N_NODES_C * 8 * 4);
    float* nsum   = (float*)take((size_t)N_NODES_C * 8 * 4);
    float* node   = (float*)take((size_t)N_NODES_C * 3200 * 4);
    u16* a_h2     = (u16*)take((size_t)E_EDGES * 64 * 2);
    // arena — aliased by phase
    char* arena   = take(173015040);
    if (off > ws_size) {  // diagnostic: paint output so the failure mode is identifiable
        k_diag<<<(out_size + 255) / 256, 256, 0, stream>>>((float*)d_out, out_size);
        return;
    }

    u16* a_ee   = (u16*)(arena + 0);           // radial phase
    u16* a_ypre = (u16*)(arena + 9437184);
    u16* a_h1   = (u16*)(arena + 12582912);
    u16* a_xe   = (u16*)(arena + 0);           // per-chunk (EC,1536); radial staging dead
    u16* a_A1   = (u16*)(arena + 37748736);    // per-chunk (EC,2432)
    u16* a_Y0   = (u16*)(arena + 97517568);    // full (E,640)
    u16* a_Y1   = (u16*)(arena + 128974848);   // full (E,512)
    u16* a_Y2   = (u16*)(arena + 154140672);   // full (E,384) -> arena end
    u16* a_A2   = (u16*)(arena + 0);           // full (E,1216); xe/A1 dead
    u16* a_Z0   = (u16*)(arena + 59768832);    // per-chunk (EC,640)
    u16* a_Z1   = (u16*)(arena + 75497472);    // per-chunk (EC,1024)
    u16* a_Z2   = (u16*)(arena + 100663296);   // per-chunk (EC,768); overlaps dead Y0 region

    // ---- weight prep ----
    k_transpose<<<48, 256, 0, stream>>>(rad_w1, w_rad1T, 192, 64);
    k_transpose<<<16, 256, 0, stream>>>(rad_w2, w_rad2T, 64, 64);
    k_transpose<<<384, 256, 0, stream>>>(rad_w3, w_rad3T, 64, 1536);
    k_transpose<<<1600, 256, 0, stream>>>(c1_w0, w_c1w0T, 640, 640);
    k_transpose<<<800, 256, 0, stream>>>(c2_w0, w_c2w0T, 320, 640);
    k_combine<<<2048, 256, 0, stream>>>(c1_wm1, w_c1m1T, 512, 256);
    k_combine<<<1152, 256, 0, stream>>>(c1_wm2, w_c1m2T, 384, 192);
    k_combine<<<2048, 256, 0, stream>>>(c2_wm1, w_c2m1T, 256, 512);
    k_combine<<<1152, 256, 0, stream>>>(c2_wm2, w_c2m2T, 192, 384);
    k_packgrid<<<30, 256, 0, stream>>>(to_grid, from_grid, w_tgP, w_fgP);
    k_init<<<128, 256, 0, stream>>>(nmax, nsum, N_NODES_C * 8);
    hipMemsetAsync(node, 0, (size_t)N_NODES_C * 3200 * 4, stream);

    // ---- radial MLP (full E) ----
    k_ee<<<(E_EDGES * 192 + 255) / 256, 256, 0, stream>>>(dist, species, snd, rcv, semb, remb, a_ee);
    k_gemm<<<dim3(192, 1), 256, 0, stream>>>(a_ee, 192, w_rad1T, 192, a_ypre, 64, 64, 192, rad_b1);
    k_ln_silu<<<6144, 256, 0, stream>>>(a_ypre, a_h1, rad_g1, rad_be1);
    k_gemm<<<dim3(192, 1), 256, 0, stream>>>(a_h1, 64, w_rad2T, 64, a_ypre, 64, 64, 64, rad_b2);
    k_ln_silu<<<6144, 256, 0, stream>>>(a_ypre, a_h2, rad_g2, rad_be2);

    // ---- chunked: x_edge gemm -> rotate -> conv1 ----
    for (int c = 0; c < 2; c++) {
        int e0 = c * EC;
        k_gemm<<<dim3(96, 12), 256, 0, stream>>>(a_h2 + (size_t)e0 * 64, 64, w_rad3T, 64,
                                                 a_xe, 1536, 1536, 64, rad_b3);
        k_rotate<<<EC / 2, 256, 0, stream>>>(nf, wig, snd, rcv, a_xe, a_A1, e0);
        k_gemm<<<dim3(96, 5), 256, 0, stream>>>(a_A1, 2432, w_c1w0T, 640,
                                                a_Y0 + (size_t)e0 * 640, 640, 640, 640, c1_b0);
        k_gemm<<<dim3(96, 4), 256, 0, stream>>>(a_A1 + 640, 2432, w_c1m1T, 1024,
                                                a_Y1 + (size_t)e0 * 512, 512, 512, 1024, nullptr);
        k_gemm<<<dim3(96, 3), 256, 0, stream>>>(a_A1 + 1664, 2432, w_c1m2T, 768,
                                                a_Y2 + (size_t)e0 * 384, 384, 384, 768, nullptr);
    }

    // ---- attention softmax pieces ----
    k_logits<<<E_EDGES, 256, 0, stream>>>(a_Y0, rcv, aln_g, aln_b, adot, logits, nmax);
    k_expsum<<<(E_EDGES * 8 + 255) / 256, 256, 0, stream>>>(logits, rcv, nmax, ealpha, nsum);

    // ---- grid nonlinearity -> packed A2 (full E, MFMA) ----
    k_grid_mfma<<<E_EDGES / 2, 256, 0, stream>>>(a_Y0, a_Y1, a_Y2, w_tgP, w_fgP, a_A2);

    // ---- chunked: conv2 -> scatter ----
    for (int c = 0; c < 2; c++) {
        int e0 = c * EC;
        k_gemm<<<dim3(96, 5), 256, 0, stream>>>(a_A2 + (size_t)e0 * 1216, 1216, w_c2w0T, 320,
                                                a_Z0, 640, 640, 320, c2_b0);
        k_gemm<<<dim3(96, 8), 256, 0, stream>>>(a_A2 + (size_t)e0 * 1216 + 320, 1216, w_c2m1T, 512,
                                                a_Z1, 1024, 1024, 512, nullptr);
        k_gemm<<<dim3(96, 6), 256, 0, stream>>>(a_A2 + (size_t)e0 * 1216 + 832, 1216, w_c2m2T, 384,
                                                a_Z2, 768, 768, 384, nullptr);
        k_scatter<<<EC / 2, 256, 0, stream>>>(a_Z0, a_Z1, a_Z2, wig, ealpha, nsum, rcv, node, e0);
    }

    // ---- output projection ----
    k_proj<<<N_NODES_C, 256, 0, stream>>>(node, proj_w, proj_b, (float*)d_out);
}

// Round 8
// 1238.593 us; speedup vs baseline: 1.1812x; 1.0507x over previous
//
#include <hip/hip_runtime.h>

typedef unsigned short u16;
typedef unsigned int u32;
typedef __attribute__((ext_vector_type(8))) short short8;
typedef __attribute__((ext_vector_type(4))) float floatx4;

#define E_EDGES 24576
#define EC 12288            // edge chunk
#define N_NODES_C 4096

__device__ __forceinline__ float bf2f(u16 u) {
    union { u32 i; float f; } v; v.i = ((u32)u) << 16; return v.f;
}
__device__ __forceinline__ u16 f2bf(float f) {
    union { float f; u32 i; } v; v.f = f;
    u32 x = v.i;
    u32 r = (x + 0x7fffu + ((x >> 16) & 1u)) >> 16;
    return (u16)r;
}
__device__ __forceinline__ u32 encf(float f) {
    union { float f; u32 i; } v; v.f = f;
    return (v.i & 0x80000000u) ? ~v.i : (v.i | 0x80000000u);
}
__device__ __forceinline__ float decf(u32 u) {
    union { u32 i; float f; } v;
    v.i = (u & 0x80000000u) ? (u ^ 0x80000000u) : ~u;
    return v.f;
}
// fast transcendentals: v_exp_f32 + v_rcp_f32
__device__ __forceinline__ float sigmoidf_(float x) { return __fdividef(1.f, 1.f + __expf(-x)); }
__device__ __forceinline__ float siluf_(float x) { return x * __fdividef(1.f, 1.f + __expf(-x)); }

// async global->LDS, 16B per lane; LDS dest must be wave-uniform base + lane*16
__device__ __forceinline__ void gld16(const u16* g, u16* l) {
    __builtin_amdgcn_global_load_lds((const __attribute__((address_space(1))) unsigned int*)g,
                                     (__attribute__((address_space(3))) unsigned int*)l, 16, 0, 0);
}

// diagnostic: ws too small -> paint output with 1000 (f32)
__global__ void k_diag(float* __restrict__ out, int n) {
    int i = blockIdx.x * 256 + threadIdx.x;
    if (i < n) out[i] = 1000.0f;
}

// ---------------- weight prep (f32 src -> bf16 transposed) ----------------
__global__ void k_transpose(const float* __restrict__ src, u16* __restrict__ dst, int K, int N) {
    int idx = blockIdx.x * 256 + threadIdx.x;
    if (idx >= K * N) return;
    int k = idx / N, n = idx % N;
    dst[n * K + k] = f2bf(src[idx]);
}
// combined complex weight, pre-transposed. src (K, 2H) f32: wa=cols[0:H), wb=cols[H:2H).
// dst (2H, 2K) bf16: dst[n][k] = k<K ? src[k][n] : (n<H ? -src[k-K][H+n] : src[k-K][n-H])
__global__ void k_combine(const float* __restrict__ src, u16* __restrict__ dst, int K, int H) {
    int total = 4 * K * H;
    int idx = blockIdx.x * 256 + threadIdx.x;
    if (idx >= total) return;
    int n = idx / (2 * K), k = idx % (2 * K);
    float v;
    if (k < K) v = src[k * 2 * H + n];
    else {
        int kk = k - K;
        if (n < H) v = -src[kk * 2 * H + H + n];
        else       v = src[kk * 2 * H + (n - H)];
    }
    dst[idx] = f2bf(v);
}

// pack to_grid (100,19) -> tgP[112][32] bf16; pack from_grid (19,100) -> fgP[32][128] bf16
__global__ void k_packgrid(const float* __restrict__ tg, const float* __restrict__ fg,
                           u16* __restrict__ tgP, u16* __restrict__ fgP) {
    int idx = blockIdx.x * 256 + threadIdx.x;
    if (idx < 112 * 32) {
        int p = idx >> 5, m = idx & 31;
        tgP[idx] = (p < 100 && m < 19) ? f2bf(tg[p * 19 + m]) : (u16)0;
    }
    int j = idx - 112 * 32;
    if (j >= 0 && j < 32 * 128) {
        int m = j >> 7, k = j & 127;
        fgP[j] = (m < 19 && k < 100) ? f2bf(fg[m * 100 + k]) : (u16)0;
    }
}

__global__ void k_init(u32* __restrict__ nmax, float* __restrict__ nsum, int n) {
    int idx = blockIdx.x * 256 + threadIdx.x;
    if (idx < n) { nmax[idx] = 0x007FFFFFu; /* enc(-inf) */ nsum[idx] = 0.f; }
}

// ---------------- edge embeddings (f32 in -> bf16 A) ----------------
__global__ void k_ee(const float* __restrict__ dist, const int* __restrict__ species,
                     const int* __restrict__ snd, const int* __restrict__ rcv,
                     const float* __restrict__ semb, const float* __restrict__ remb,
                     u16* __restrict__ ee) {
    int idx = blockIdx.x * 256 + threadIdx.x;
    if (idx >= E_EDGES * 192) return;
    int e = idx / 192, c = idx % 192;
    float v;
    if (c < 64)       v = dist[e * 64 + c];
    else if (c < 128) v = semb[species[snd[e]] * 64 + (c - 64)];
    else              v = remb[species[rcv[e]] * 64 + (c - 128)];
    ee[idx] = f2bf(v);
}

// ---------------- GEMM (m97 structure): A (M,K) bf16 rm, BT (N,K) bf16 rm, C (M,N) bf16 ----------------
// global_load_lds staging, unpadded 64B rows. M%128==0, K%32==0; N guarded.
// Explicit s_waitcnt vmcnt(0) before barrier — async LDS-DMA must drain (round-6 race fix).
__global__ __launch_bounds__(256) void k_gemm(
    const u16* __restrict__ A, int lda,
    const u16* __restrict__ BT, int ldb,
    u16* __restrict__ C, int ldc,
    int N, int K,
    const float* __restrict__ bias) {
    __shared__ u16 As[128 * 32];
    __shared__ u16 Bs[128 * 32];
    int tid = threadIdx.x;
    int bm0 = blockIdx.x * 128;
    int bn0 = blockIdx.y * 128;
    int wave = tid >> 6, lane = tid & 63;
    int wm = (wave >> 1) * 64, wn = (wave & 1) * 64;
    int lrow = lane & 15, lk = (lane >> 4) * 8;

    // staging geometry: wave w covers rows w*16 + (lane>>2), 16B chunk (lane&3)
    int srow = (wave << 4) + (lane >> 2);        // 0..63
    int schunk = (lane & 3) << 3;                // u16 offset 0/8/16/24
    const u16* Arow0 = A + (size_t)(bm0 + srow) * lda + schunk;
    const u16* Arow1 = A + (size_t)(bm0 + srow + 64) * lda + schunk;
    int n0 = bn0 + srow;      if (n0 >= N) n0 = N - 1;
    int n1 = bn0 + srow + 64; if (n1 >= N) n1 = N - 1;
    const u16* Brow0 = BT + (size_t)n0 * ldb + schunk;
    const u16* Brow1 = BT + (size_t)n1 * ldb + schunk;
    u16* lA0 = &As[srow * 32 + schunk];
    u16* lA1 = &As[(srow + 64) * 32 + schunk];
    u16* lB0 = &Bs[srow * 32 + schunk];
    u16* lB1 = &Bs[(srow + 64) * 32 + schunk];

    floatx4 acc[4][4];
#pragma unroll
    for (int i = 0; i < 4; i++)
#pragma unroll
        for (int j = 0; j < 4; j++) acc[i][j] = floatx4{0.f, 0.f, 0.f, 0.f};

    for (int k0 = 0; k0 < K; k0 += 32) {
        gld16(Arow0 + k0, lA0);
        gld16(Arow1 + k0, lA1);
        gld16(Brow0 + k0, lB0);
        gld16(Brow1 + k0, lB1);
        asm volatile("s_waitcnt vmcnt(0)" ::: "memory");
        __syncthreads();
        short8 a[4], b[4];
#pragma unroll
        for (int i = 0; i < 4; i++) a[i] = *(const short8*)(&As[(wm + i * 16 + lrow) * 32 + lk]);
#pragma unroll
        for (int j = 0; j < 4; j++) b[j] = *(const short8*)(&Bs[(wn + j * 16 + lrow) * 32 + lk]);
#pragma unroll
        for (int i = 0; i < 4; i++)
#pragma unroll
            for (int j = 0; j < 4; j++)
                acc[i][j] = __builtin_amdgcn_mfma_f32_16x16x32_bf16(a[i], b[j], acc[i][j], 0, 0, 0);
        __syncthreads();
    }

    int q = lane >> 4;
#pragma unroll
    for (int i = 0; i < 4; i++) {
#pragma unroll
        for (int j = 0; j < 4; j++) {
            int col = bn0 + wn + j * 16 + lrow;
            if (col < N) {
                float bv = bias ? bias[col] : 0.f;
#pragma unroll
                for (int r = 0; r < 4; r++) {
                    int row = bm0 + wm + i * 16 + q * 4 + r;
                    C[(size_t)row * ldc + col] = f2bf(acc[i][j][r] + bv);
                }
            }
        }
    }
}

// ---------------- LayerNorm(64) + SiLU (bf16 io, f32 params) ----------------
__global__ __launch_bounds__(256) void k_ln_silu(const u16* __restrict__ in, u16* __restrict__ out,
                                                 const float* __restrict__ g, const float* __restrict__ b) {
    int tid = threadIdx.x;
    int e = blockIdx.x * 4 + (tid >> 6);
    int c = tid & 63;
    float x = bf2f(in[(size_t)e * 64 + c]);
    float s = x, s2 = x * x;
#pragma unroll
    for (int o = 32; o; o >>= 1) { s += __shfl_xor(s, o); s2 += __shfl_xor(s2, o); }
    float mu = s * (1.f / 64.f);
    float var = s2 * (1.f / 64.f) - mu * mu;
    float rs = rsqrtf(var + 1e-5f);
    float y = (x - mu) * rs * g[c] + b[c];
    out[(size_t)e * 64 + c] = f2bf(siluf_(y));
}

// ---------------- rotate: wigner @ concat(nf[snd],nf[rcv]); scale by x_edge; pack A1 (chunked) ----------------
__global__ __launch_bounds__(256) void k_rotate(const float* __restrict__ nf, const float* __restrict__ wig,
                                                const int* __restrict__ snd, const int* __restrict__ rcv,
                                                const u16* __restrict__ xe, u16* __restrict__ A1, int e0) {
    __shared__ float wl[2][475];
    int tid = threadIdx.x;
    for (int i = tid; i < 950; i += 256) {
        int ee = e0 + blockIdx.x * 2 + (i / 475);
        wl[i / 475][i % 475] = wig[(size_t)ee * 475 + (i % 475)];
    }
    __syncthreads();
    int le = tid >> 7, c = tid & 127;
    int el = blockIdx.x * 2 + le;       // chunk-local
    int e = e0 + el;                    // global
    int nd = (c < 64) ? snd[e] : rcv[e];
    int cc = c & 63;
    float msg[25];
#pragma unroll
    for (int k = 0; k < 25; k++) msg[k] = nf[(size_t)nd * 1600 + k * 64 + cc];
    const float* w = wl[le];
    size_t ebase = (size_t)el * 2432;
    size_t xbase = (size_t)el * 1536;
#pragma unroll
    for (int m = 0; m < 19; m++) {
        float r = 0.f;
#pragma unroll
        for (int k = 0; k < 25; k++) r += w[m * 25 + k] * msg[k];
        int a1c, xc;
        if (m < 5)       { a1c = m * 128;               xc = m * 128; }
        else if (m < 9)  { a1c = 640 + (m - 5) * 128;   xc = 640 + (m - 5) * 128; }
        else if (m < 13) { a1c = 1152 + (m - 9) * 128;  xc = 640 + (m - 9) * 128; }
        else if (m < 16) { a1c = 1664 + (m - 13) * 128; xc = 1152 + (m - 13) * 128; }
        else             { a1c = 2048 + (m - 16) * 128; xc = 1152 + (m - 16) * 128; }
        float sc = bf2f(xe[xbase + xc + c]);
        A1[ebase + a1c + c] = f2bf(r * sc);
    }
}

// ---------------- attention logits + segment max ----------------
__global__ __launch_bounds__(256) void k_logits(const u16* __restrict__ Y0, const int* __restrict__ rcv,
                                                const float* __restrict__ g, const float* __restrict__ b,
                                                const float* __restrict__ adot,
                                                float* __restrict__ logits, u32* __restrict__ nmax) {
    int e = blockIdx.x;
    int tid = threadIdx.x;
    int h = tid >> 5, c = tid & 31;
    float x = bf2f(Y0[(size_t)e * 640 + 320 + h * 32 + c]);
    float s = x, s2 = x * x;
#pragma unroll
    for (int o = 16; o; o >>= 1) { s += __shfl_xor(s, o); s2 += __shfl_xor(s2, o); }
    float mu = s * (1.f / 32.f);
    float var = s2 * (1.f / 32.f) - mu * mu;
    float rs = rsqrtf(var + 1e-5f);
    float a = (x - mu) * rs * g[c] + b[c];
    float f = 0.6f * a + 0.4f * a * (2.f * sigmoidf_(a) - 1.f);
    float l = f * adot[h * 32 + c];
#pragma unroll
    for (int o = 16; o; o >>= 1) l += __shfl_xor(l, o);
    if (c == 0) {
        logits[e * 8 + h] = l;
        atomicMax(&nmax[rcv[e] * 8 + h], encf(l));
    }
}

__global__ void k_expsum(const float* __restrict__ logits, const int* __restrict__ rcv,
                         const u32* __restrict__ nmax, float* __restrict__ ealpha, float* __restrict__ nsum) {
    int idx = blockIdx.x * 256 + threadIdx.x;
    if (idx >= E_EDGES * 8) return;
    int e = idx >> 3, h = idx & 7;
    int r = rcv[e];
    float amax = decf(nmax[r * 8 + h]);
    if (!(amax > -1e38f && amax < 1e38f)) amax = 0.f;
    float v = __expf(logits[idx] - amax);
    ealpha[idx] = v;
    atomicAdd(&nsum[r * 8 + h], v);
}

// ---------------- grid round-trip via MFMA ----------------
// Per block: 2 edges -> 128 (e,c) rows. T1 = X(128x32) @ tgP^T -> silu -> T2 = T1(128x128) @ fgP^T.
// v2: vectorized staging (uint4) + direct packed-uint2 store of acc2 (no LDS round-trip).
#define GR_XS_STR 40
#define GR_T1_STR 136
__global__ __launch_bounds__(256) void k_grid_mfma(
    const u16* __restrict__ Y0, const u16* __restrict__ Y1, const u16* __restrict__ Y2,
    const u16* __restrict__ tgP, const u16* __restrict__ fgP, u16* __restrict__ A2) {
    __shared__ u16 Xs[128 * GR_XS_STR];
    __shared__ u16 T1s[128 * GR_T1_STR];
    int tid = threadIdx.x;
    int e0 = blockIdx.x * 2;
    // zero T1s pad cols 112..127
    {
        int row = tid >> 1;
        uint4 z = {0, 0, 0, 0};
        *(uint4*)(&T1s[row * GR_T1_STR + 112 + (tid & 1) * 8]) = z;
    }
    // stage Xs[row][m] via uint4 loads: i in [0,512): le=i>>8, m=(i>>3)&31, chunk=i&7
#pragma unroll
    for (int it = 0; it < 2; it++) {
        int i = tid + it * 256;
        int le = i >> 8;
        int m = (i >> 3) & 31;
        int c0 = (i & 7) << 3;
        int e = e0 + le;
        uint4 v = {0, 0, 0, 0};
        if (m < 5)       v = *(const uint4*)(&Y0[(size_t)e * 640 + m * 64 + c0]);
        else if (m < 13) v = *(const uint4*)(&Y1[(size_t)e * 512 + (m - 5) * 64 + c0]);
        else if (m < 19) v = *(const uint4*)(&Y2[(size_t)e * 384 + (m - 13) * 64 + c0]);
        const u16* pv = (const u16*)&v;
        int rbase = le * 64 + c0;
#pragma unroll
        for (int j = 0; j < 8; j++)
            Xs[(rbase + j) * GR_XS_STR + m] = pv[j];
    }
    __syncthreads();
    int wave = tid >> 6, lane = tid & 63;
    int wr = wave * 32;
    int ln = lane & 15, q = lane >> 4;
    // GEMM1: single K-step (K=32)
    short8 a0 = *(const short8*)(&Xs[(wr + ln) * GR_XS_STR + q * 8]);
    short8 a1 = *(const short8*)(&Xs[(wr + 16 + ln) * GR_XS_STR + q * 8]);
    floatx4 acc1[2][7];
#pragma unroll
    for (int pt = 0; pt < 7; pt++) {
        short8 b = *(const short8*)(&tgP[(size_t)(pt * 16 + ln) * 32 + q * 8]);
        acc1[0][pt] = __builtin_amdgcn_mfma_f32_16x16x32_bf16(a0, b, floatx4{0.f, 0.f, 0.f, 0.f}, 0, 0, 0);
        acc1[1][pt] = __builtin_amdgcn_mfma_f32_16x16x32_bf16(a1, b, floatx4{0.f, 0.f, 0.f, 0.f}, 0, 0, 0);
    }
    // silu -> T1s (skip pad cols >= 100: pt==6 && ln>=4)
#pragma unroll
    for (int rt = 0; rt < 2; rt++)
#pragma unroll
        for (int pt = 0; pt < 7; pt++) {
            bool pad = (pt == 6) && (ln >= 4);
#pragma unroll
            for (int r = 0; r < 4; r++) {
                int row = wr + rt * 16 + q * 4 + r;
                T1s[row * GR_T1_STR + pt * 16 + ln] = pad ? (u16)0 : f2bf(siluf_(acc1[rt][pt][r]));
            }
        }
    __syncthreads();
    // GEMM2: K=128 (4 steps)
    floatx4 acc2[2][2];
    acc2[0][0] = floatx4{0.f, 0.f, 0.f, 0.f}; acc2[0][1] = floatx4{0.f, 0.f, 0.f, 0.f};
    acc2[1][0] = floatx4{0.f, 0.f, 0.f, 0.f}; acc2[1][1] = floatx4{0.f, 0.f, 0.f, 0.f};
#pragma unroll
    for (int ks = 0; ks < 4; ks++) {
        short8 c0 = *(const short8*)(&T1s[(wr + ln) * GR_T1_STR + ks * 32 + q * 8]);
        short8 c1 = *(const short8*)(&T1s[(wr + 16 + ln) * GR_T1_STR + ks * 32 + q * 8]);
#pragma unroll
        for (int ct = 0; ct < 2; ct++) {
            short8 b = *(const short8*)(&fgP[(size_t)(ct * 16 + ln) * 128 + ks * 32 + q * 8]);
            acc2[0][ct] = __builtin_amdgcn_mfma_f32_16x16x32_bf16(c0, b, acc2[0][ct], 0, 0, 0);
            acc2[1][ct] = __builtin_amdgcn_mfma_f32_16x16x32_bf16(c1, b, acc2[1][ct], 0, 0, 0);
        }
    }
    // direct store: lane holds col m'=ct*16+ln, rows q*4+r -> 4 consecutive c in A2
#pragma unroll
    for (int rt = 0; rt < 2; rt++) {
        int row = wr + rt * 16 + q * 4;
        int e = e0 + (row >> 6), c = row & 63;
#pragma unroll
        for (int ct = 0; ct < 2; ct++) {
            int mp = ct * 16 + ln;
            if (mp >= 1 && mp < 19) {
                uint2 pv;
                pv.x = (u32)f2bf(acc2[rt][ct][0]) | ((u32)f2bf(acc2[rt][ct][1]) << 16);
                pv.y = (u32)f2bf(acc2[rt][ct][2]) | ((u32)f2bf(acc2[rt][ct][3]) << 16);
                *(uint2*)(&A2[(size_t)e * 1216 + mp * 64 + c]) = pv;
            }
        }
    }
    // m=0 gate row
    if (tid < 128) {
        int e = e0 + (tid >> 6), c = tid & 63;
        float gate = bf2f(Y0[(size_t)e * 640 + 576 + c]);
        A2[(size_t)e * 1216 + c] = f2bf(siluf_(gate));
    }
}

// ---------------- attention scale + wigner^T + segment-sum into node (chunked) ----------------
__global__ __launch_bounds__(256) void k_scatter(const u16* __restrict__ Z0, const u16* __restrict__ Z1,
                                                 const u16* __restrict__ Z2, const float* __restrict__ wig,
                                                 const float* __restrict__ ealpha, const float* __restrict__ nsum,
                                                 const int* __restrict__ rcv, float* __restrict__ node, int e0) {
    __shared__ float wl[2][475];
    int tid = threadIdx.x;
    for (int i = tid; i < 950; i += 256) {
        int ee = e0 + blockIdx.x * 2 + (i / 475);
        wl[i / 475][i % 475] = wig[(size_t)ee * 475 + (i % 475)];
    }
    __syncthreads();
    int le = tid >> 7, c = tid & 127;
    int el = blockIdx.x * 2 + le;
    int e = e0 + el;
    int r = rcv[e];
    int h = c >> 4;
    float al = ealpha[e * 8 + h] / (nsum[r * 8 + h] + 1e-16f);
    float s[19];
#pragma unroll
    for (int m = 0; m < 19; m++) {
        float v;
        if (m < 5)       v = bf2f(Z0[(size_t)el * 640 + m * 128 + c]);
        else if (m < 13) v = bf2f(Z1[(size_t)el * 1024 + (m - 5) * 128 + c]);
        else             v = bf2f(Z2[(size_t)el * 768 + (m - 13) * 128 + c]);
        s[m] = v * al;
    }
    const float* w = wl[le];
    float* nb = node + (size_t)r * 3200 + c;
#pragma unroll
    for (int k = 0; k < 25; k++) {
        float acc = 0.f;
#pragma unroll
        for (int m = 0; m < 19; m++) acc += w[m * 25 + k] * s[m];
        atomicAdd(&nb[k * 128], acc);
    }
}

// ---------------- final projection (f32 node, f32 weights, f32 out) ----------------
__global__ void k_proj(const float* __restrict__ node, const float* __restrict__ pw,
                       const float* __restrict__ pb, float* __restrict__ out) {
    int n = blockIdx.x;
    int tid = threadIdx.x;
    int d = tid & 63, kk = tid >> 6;
    for (int k = kk; k < 25; k += 4) {
        int l = (int)sqrtf((float)k + 0.5f);
        const float* nr = node + (size_t)n * 3200 + k * 128;
        const float* w = pw + (size_t)l * 8192 + d;
        float acc = 0.f;
#pragma unroll 8
        for (int c = 0; c < 128; c++) acc += nr[c] * w[c * 64];
        if (k == 0) acc += pb[d];
        out[(size_t)n * 1600 + k * 64 + d] = acc;
    }
}

extern "C" void kernel_launch(void* const* d_in, const int* in_sizes, int n_in,
                              void* d_out, int out_size, void* d_ws, size_t ws_size,
                              hipStream_t stream) {
    const float* nf      = (const float*)d_in[0];
    const int* species   = (const int*)d_in[1];
    const float* dist    = (const float*)d_in[2];
    const int* snd       = (const int*)d_in[3];
    const int* rcv       = (const int*)d_in[4];
    const float* wig     = (const float*)d_in[5];
    const float* semb    = (const float*)d_in[6];
    const float* remb    = (const float*)d_in[7];
    const float* rad_w1  = (const float*)d_in[8];
    const float* rad_b1  = (const float*)d_in[9];
    const float* rad_g1  = (const float*)d_in[10];
    const float* rad_be1 = (const float*)d_in[11];
    const float* rad_w2  = (const float*)d_in[12];
    const float* rad_b2  = (const float*)d_in[13];
    const float* rad_g2  = (const float*)d_in[14];
    const float* rad_be2 = (const float*)d_in[15];
    const float* rad_w3  = (const float*)d_in[16];
    const float* rad_b3  = (const float*)d_in[17];
    const float* c1_w0   = (const float*)d_in[18];
    const float* c1_b0   = (const float*)d_in[19];
    const float* c1_wm1  = (const float*)d_in[20];
    const float* c1_wm2  = (const float*)d_in[21];
    const float* aln_g   = (const float*)d_in[22];
    const float* aln_b   = (const float*)d_in[23];
    const float* adot    = (const float*)d_in[24];
    const float* to_grid = (const float*)d_in[25];
    const float* from_grid=(const float*)d_in[26];
    const float* c2_w0   = (const float*)d_in[27];
    const float* c2_b0   = (const float*)d_in[28];
    const float* c2_wm1  = (const float*)d_in[29];
    const float* c2_wm2  = (const float*)d_in[30];
    const float* proj_w  = (const float*)d_in[31];
    const float* proj_b  = (const float*)d_in[32];

    char* ws = (char*)d_ws;
    size_t off = 0;
    auto take = [&](size_t bytes) -> char* {
        char* p = ws + off;
        off += (bytes + 255) & ~(size_t)255;
        return p;
    };
    // fixed section
    u16* w_rad1T  = (u16*)take(64 * 192 * 2);
    u16* w_rad2T  = (u16*)take(64 * 64 * 2);
    u16* w_rad3T  = (u16*)take(1536 * 64 * 2);
    u16* w_c1w0T  = (u16*)take(640 * 640 * 2);
    u16* w_c1m1T  = (u16*)take((size_t)512 * 1024 * 2);
    u16* w_c1m2T  = (u16*)take((size_t)384 * 768 * 2);
    u16* w_c2w0T  = (u16*)take((size_t)640 * 320 * 2);
    u16* w_c2m1T  = (u16*)take((size_t)1024 * 512 * 2);
    u16* w_c2m2T  = (u16*)take((size_t)768 * 384 * 2);
    u16* w_tgP    = (u16*)take(112 * 32 * 2);
    u16* w_fgP    = (u16*)take(32 * 128 * 2);
    float* logits = (float*)take((size_t)E_EDGES * 8 * 4);
    float* ealpha = (float*)take((size_t)E_EDGES * 8 * 4);
    u32* nmax     = (u32*)take((size_t)N_NODES_C * 8 * 4);
    float* nsum   = (float*)take((size_t)N_NODES_C * 8 * 4);
    float* node   = (float*)take((size_t)N_NODES_C * 3200 * 4);
    u16* a_h2     = (u16*)take((size_t)E_EDGES * 64 * 2);
    // arena — aliased by phase
    char* arena   = take(173015040);
    if (off > ws_size) {  // diagnostic: paint output so the failure mode is identifiable
        k_diag<<<(out_size + 255) / 256, 256, 0, stream>>>((float*)d_out, out_size);
        return;
    }

    u16* a_ee   = (u16*)(arena + 0);           // radial phase
    u16* a_ypre = (u16*)(arena + 9437184);
    u16* a_h1   = (u16*)(arena + 12582912);
    u16* a_xe   = (u16*)(arena + 0);           // per-chunk (EC,1536); radial staging dead
    u16* a_A1   = (u16*)(arena + 37748736);    // per-chunk (EC,2432)
    u16* a_Y0   = (u16*)(arena + 97517568);    // full (E,640)
    u16* a_Y1   = (u16*)(arena + 128974848);   // full (E,512)
    u16* a_Y2   = (u16*)(arena + 154140672);   // full (E,384) -> arena end
    u16* a_A2   = (u16*)(arena + 0);           // full (E,1216); xe/A1 dead
    u16* a_Z0   = (u16*)(arena + 59768832);    // per-chunk (EC,640)
    u16* a_Z1   = (u16*)(arena + 75497472);    // per-chunk (EC,1024)
    u16* a_Z2   = (u16*)(arena + 100663296);   // per-chunk (EC,768); overlaps dead Y0 region

    // ---- weight prep ----
    k_transpose<<<48, 256, 0, stream>>>(rad_w1, w_rad1T, 192, 64);
    k_transpose<<<16, 256, 0, stream>>>(rad_w2, w_rad2T, 64, 64);
    k_transpose<<<384, 256, 0, stream>>>(rad_w3, w_rad3T, 64, 1536);
    k_transpose<<<1600, 256, 0, stream>>>(c1_w0, w_c1w0T, 640, 640);
    k_transpose<<<800, 256, 0, stream>>>(c2_w0, w_c2w0T, 320, 640);
    k_combine<<<2048, 256, 0, stream>>>(c1_wm1, w_c1m1T, 512, 256);
    k_combine<<<1152, 256, 0, stream>>>(c1_wm2, w_c1m2T, 384, 192);
    k_combine<<<2048, 256, 0, stream>>>(c2_wm1, w_c2m1T, 256, 512);
    k_combine<<<1152, 256, 0, stream>>>(c2_wm2, w_c2m2T, 192, 384);
    k_packgrid<<<30, 256, 0, stream>>>(to_grid, from_grid, w_tgP, w_fgP);
    k_init<<<128, 256, 0, stream>>>(nmax, nsum, N_NODES_C * 8);
    hipMemsetAsync(node, 0, (size_t)N_NODES_C * 3200 * 4, stream);

    // ---- radial MLP (full E) ----
    k_ee<<<(E_EDGES * 192 + 255) / 256, 256, 0, stream>>>(dist, species, snd, rcv, semb, remb, a_ee);
    k_gemm<<<dim3(192, 1), 256, 0, stream>>>(a_ee, 192, w_rad1T, 192, a_ypre, 64, 64, 192, rad_b1);
    k_ln_silu<<<6144, 256, 0, stream>>>(a_ypre, a_h1, rad_g1, rad_be1);
    k_gemm<<<dim3(192, 1), 256, 0, stream>>>(a_h1, 64, w_rad2T, 64, a_ypre, 64, 64, 64, rad_b2);
    k_ln_silu<<<6144, 256, 0, stream>>>(a_ypre, a_h2, rad_g2, rad_be2);

    // ---- chunked: x_edge gemm -> rotate -> conv1 ----
    for (int c = 0; c < 2; c++) {
        int e0 = c * EC;
        k_gemm<<<dim3(96, 12), 256, 0, stream>>>(a_h2 + (size_t)e0 * 64, 64, w_rad3T, 64,
                                                 a_xe, 1536, 1536, 64, rad_b3);
        k_rotate<<<EC / 2, 256, 0, stream>>>(nf, wig, snd, rcv, a_xe, a_A1, e0);
        k_gemm<<<dim3(96, 5), 256, 0, stream>>>(a_A1, 2432, w_c1w0T, 640,
                                                a_Y0 + (size_t)e0 * 640, 640, 640, 640, c1_b0);
        k_gemm<<<dim3(96, 4), 256, 0, stream>>>(a_A1 + 640, 2432, w_c1m1T, 1024,
                                                a_Y1 + (size_t)e0 * 512, 512, 512, 1024, nullptr);
        k_gemm<<<dim3(96, 3), 256, 0, stream>>>(a_A1 + 1664, 2432, w_c1m2T, 768,
                                                a_Y2 + (size_t)e0 * 384, 384, 384, 768, nullptr);
    }

    // ---- attention softmax pieces ----
    k_logits<<<E_EDGES, 256, 0, stream>>>(a_Y0, rcv, aln_g, aln_b, adot, logits, nmax);
    k_expsum<<<(E_EDGES * 8 + 255) / 256, 256, 0, stream>>>(logits, rcv, nmax, ealpha, nsum);

    // ---- grid nonlinearity -> packed A2 (full E, MFMA) ----
    k_grid_mfma<<<E_EDGES / 2, 256, 0, stream>>>(a_Y0, a_Y1, a_Y2, w_tgP, w_fgP, a_A2);

    // ---- chunked: conv2 -> scatter ----
    for (int c = 0; c < 2; c++) {
        int e0 = c * EC;
        k_gemm<<<dim3(96, 5), 256, 0, stream>>>(a_A2 + (size_t)e0 * 1216, 1216, w_c2w0T, 320,
                                                a_Z0, 640, 640, 320, c2_b0);
        k_gemm<<<dim3(96, 8), 256, 0, stream>>>(a_A2 + (size_t)e0 * 1216 + 320, 1216, w_c2m1T, 512,
                                                a_Z1, 1024, 1024, 512, nullptr);
        k_gemm<<<dim3(96, 6), 256, 0, stream>>>(a_A2 + (size_t)e0 * 1216 + 832, 1216, w_c2m2T, 384,
                                                a_Z2, 768, 768, 384, nullptr);
        k_scatter<<<EC / 2, 256, 0, stream>>>(a_Z0, a_Z1, a_Z2, wig, ealpha, nsum, rcv, node, e0);
    }

    // ---- output projection ----
    k_proj<<<N_NODES_C, 256, 0, stream>>>(node, proj_w, proj_b, (float*)d_out);
}

// Round 9
// 1077.474 us; speedup vs baseline: 1.3578x; 1.1495x over previous
//
#include <hip/hip_runtime.h>

typedef unsigned short u16;
typedef unsigned int u32;
typedef __attribute__((ext_vector_type(8))) short short8;
typedef __attribute__((ext_vector_type(4))) float floatx4;

#define E_EDGES 24576
#define EC 12288            // edge chunk
#define N_NODES_C 4096

__device__ __forceinline__ float bf2f(u16 u) {
    union { u32 i; float f; } v; v.i = ((u32)u) << 16; return v.f;
}
__device__ __forceinline__ u16 f2bf(float f) {
    union { float f; u32 i; } v; v.f = f;
    u32 x = v.i;
    u32 r = (x + 0x7fffu + ((x >> 16) & 1u)) >> 16;
    return (u16)r;
}
__device__ __forceinline__ u32 encf(float f) {
    union { float f; u32 i; } v; v.f = f;
    return (v.i & 0x80000000u) ? ~v.i : (v.i | 0x80000000u);
}
__device__ __forceinline__ float decf(u32 u) {
    union { u32 i; float f; } v;
    v.i = (u & 0x80000000u) ? (u ^ 0x80000000u) : ~u;
    return v.f;
}
// fast transcendentals: v_exp_f32 + v_rcp_f32
__device__ __forceinline__ float sigmoidf_(float x) { return __fdividef(1.f, 1.f + __expf(-x)); }
__device__ __forceinline__ float siluf_(float x) { return x * __fdividef(1.f, 1.f + __expf(-x)); }

// async global->LDS, 16B per lane; LDS dest must be wave-uniform base + lane*16
__device__ __forceinline__ void gld16(const u16* g, u16* l) {
    __builtin_amdgcn_global_load_lds((const __attribute__((address_space(1))) unsigned int*)g,
                                     (__attribute__((address_space(3))) unsigned int*)l, 16, 0, 0);
}

// diagnostic: ws too small -> paint output with 1000 (f32)
__global__ void k_diag(float* __restrict__ out, int n) {
    int i = blockIdx.x * 256 + threadIdx.x;
    if (i < n) out[i] = 1000.0f;
}

// ---------------- weight prep (f32 src -> bf16 transposed) ----------------
__global__ void k_transpose(const float* __restrict__ src, u16* __restrict__ dst, int K, int N) {
    int idx = blockIdx.x * 256 + threadIdx.x;
    if (idx >= K * N) return;
    int k = idx / N, n = idx % N;
    dst[n * K + k] = f2bf(src[idx]);
}
// combined complex weight, pre-transposed. src (K, 2H) f32: wa=cols[0:H), wb=cols[H:2H).
// dst (2H, 2K) bf16: dst[n][k] = k<K ? src[k][n] : (n<H ? -src[k-K][H+n] : src[k-K][n-H])
__global__ void k_combine(const float* __restrict__ src, u16* __restrict__ dst, int K, int H) {
    int total = 4 * K * H;
    int idx = blockIdx.x * 256 + threadIdx.x;
    if (idx >= total) return;
    int n = idx / (2 * K), k = idx % (2 * K);
    float v;
    if (k < K) v = src[k * 2 * H + n];
    else {
        int kk = k - K;
        if (n < H) v = -src[kk * 2 * H + H + n];
        else       v = src[kk * 2 * H + (n - H)];
    }
    dst[idx] = f2bf(v);
}

// pack to_grid (100,19) -> tgP[112][32] bf16; pack from_grid (19,100) -> fgP[32][128] bf16
__global__ void k_packgrid(const float* __restrict__ tg, const float* __restrict__ fg,
                           u16* __restrict__ tgP, u16* __restrict__ fgP) {
    int idx = blockIdx.x * 256 + threadIdx.x;
    if (idx < 112 * 32) {
        int p = idx >> 5, m = idx & 31;
        tgP[idx] = (p < 100 && m < 19) ? f2bf(tg[p * 19 + m]) : (u16)0;
    }
    int j = idx - 112 * 32;
    if (j >= 0 && j < 32 * 128) {
        int m = j >> 7, k = j & 127;
        fgP[j] = (m < 19 && k < 100) ? f2bf(fg[m * 100 + k]) : (u16)0;
    }
}

__global__ void k_init(u32* __restrict__ nmax, float* __restrict__ nsum, int n) {
    int idx = blockIdx.x * 256 + threadIdx.x;
    if (idx < n) { nmax[idx] = 0x007FFFFFu; /* enc(-inf) */ nsum[idx] = 0.f; }
}

// ---------------- edge embeddings (f32 in -> bf16 A) ----------------
__global__ void k_ee(const float* __restrict__ dist, const int* __restrict__ species,
                     const int* __restrict__ snd, const int* __restrict__ rcv,
                     const float* __restrict__ semb, const float* __restrict__ remb,
                     u16* __restrict__ ee) {
    int idx = blockIdx.x * 256 + threadIdx.x;
    if (idx >= E_EDGES * 192) return;
    int e = idx / 192, c = idx % 192;
    float v;
    if (c < 64)       v = dist[e * 64 + c];
    else if (c < 128) v = semb[species[snd[e]] * 64 + (c - 64)];
    else              v = remb[species[rcv[e]] * 64 + (c - 128)];
    ee[idx] = f2bf(v);
}

// ---------------- GEMM (m97 structure): A (M,K) bf16 rm, BT (N,K) bf16 rm, C (M,N) bf16 ----------------
// global_load_lds staging, unpadded 64B rows. M%128==0, K%32==0; N guarded.
// Explicit s_waitcnt vmcnt(0) before barrier — async LDS-DMA must drain (round-6 race fix).
__global__ __launch_bounds__(256) void k_gemm(
    const u16* __restrict__ A, int lda,
    const u16* __restrict__ BT, int ldb,
    u16* __restrict__ C, int ldc,
    int N, int K,
    const float* __restrict__ bias) {
    __shared__ u16 As[128 * 32];
    __shared__ u16 Bs[128 * 32];
    int tid = threadIdx.x;
    int bm0 = blockIdx.x * 128;
    int bn0 = blockIdx.y * 128;
    int wave = tid >> 6, lane = tid & 63;
    int wm = (wave >> 1) * 64, wn = (wave & 1) * 64;
    int lrow = lane & 15, lk = (lane >> 4) * 8;

    // staging geometry: wave w covers rows w*16 + (lane>>2), 16B chunk (lane&3)
    int srow = (wave << 4) + (lane >> 2);        // 0..63
    int schunk = (lane & 3) << 3;                // u16 offset 0/8/16/24
    const u16* Arow0 = A + (size_t)(bm0 + srow) * lda + schunk;
    const u16* Arow1 = A + (size_t)(bm0 + srow + 64) * lda + schunk;
    int n0 = bn0 + srow;      if (n0 >= N) n0 = N - 1;
    int n1 = bn0 + srow + 64; if (n1 >= N) n1 = N - 1;
    const u16* Brow0 = BT + (size_t)n0 * ldb + schunk;
    const u16* Brow1 = BT + (size_t)n1 * ldb + schunk;
    u16* lA0 = &As[srow * 32 + schunk];
    u16* lA1 = &As[(srow + 64) * 32 + schunk];
    u16* lB0 = &Bs[srow * 32 + schunk];
    u16* lB1 = &Bs[(srow + 64) * 32 + schunk];

    floatx4 acc[4][4];
#pragma unroll
    for (int i = 0; i < 4; i++)
#pragma unroll
        for (int j = 0; j < 4; j++) acc[i][j] = floatx4{0.f, 0.f, 0.f, 0.f};

    for (int k0 = 0; k0 < K; k0 += 32) {
        gld16(Arow0 + k0, lA0);
        gld16(Arow1 + k0, lA1);
        gld16(Brow0 + k0, lB0);
        gld16(Brow1 + k0, lB1);
        asm volatile("s_waitcnt vmcnt(0)" ::: "memory");
        __syncthreads();
        short8 a[4], b[4];
#pragma unroll
        for (int i = 0; i < 4; i++) a[i] = *(const short8*)(&As[(wm + i * 16 + lrow) * 32 + lk]);
#pragma unroll
        for (int j = 0; j < 4; j++) b[j] = *(const short8*)(&Bs[(wn + j * 16 + lrow) * 32 + lk]);
#pragma unroll
        for (int i = 0; i < 4; i++)
#pragma unroll
            for (int j = 0; j < 4; j++)
                acc[i][j] = __builtin_amdgcn_mfma_f32_16x16x32_bf16(a[i], b[j], acc[i][j], 0, 0, 0);
        __syncthreads();
    }

    int q = lane >> 4;
#pragma unroll
    for (int i = 0; i < 4; i++) {
#pragma unroll
        for (int j = 0; j < 4; j++) {
            int col = bn0 + wn + j * 16 + lrow;
            if (col < N) {
                float bv = bias ? bias[col] : 0.f;
#pragma unroll
                for (int r = 0; r < 4; r++) {
                    int row = bm0 + wm + i * 16 + q * 4 + r;
                    C[(size_t)row * ldc + col] = f2bf(acc[i][j][r] + bv);
                }
            }
        }
    }
}

// ---------------- LayerNorm(64) + SiLU (bf16 io, f32 params) ----------------
__global__ __launch_bounds__(256) void k_ln_silu(const u16* __restrict__ in, u16* __restrict__ out,
                                                 const float* __restrict__ g, const float* __restrict__ b) {
    int tid = threadIdx.x;
    int e = blockIdx.x * 4 + (tid >> 6);
    int c = tid & 63;
    float x = bf2f(in[(size_t)e * 64 + c]);
    float s = x, s2 = x * x;
#pragma unroll
    for (int o = 32; o; o >>= 1) { s += __shfl_xor(s, o); s2 += __shfl_xor(s2, o); }
    float mu = s * (1.f / 64.f);
    float var = s2 * (1.f / 64.f) - mu * mu;
    float rs = rsqrtf(var + 1e-5f);
    float y = (x - mu) * rs * g[c] + b[c];
    out[(size_t)e * 64 + c] = f2bf(siluf_(y));
}

// ---------------- rotate: wigner @ concat(nf[snd],nf[rcv]); scale by x_edge; pack A1 (chunked) ----------------
__global__ __launch_bounds__(256) void k_rotate(const float* __restrict__ nf, const float* __restrict__ wig,
                                                const int* __restrict__ snd, const int* __restrict__ rcv,
                                                const u16* __restrict__ xe, u16* __restrict__ A1, int e0) {
    __shared__ float wl[2][475];
    int tid = threadIdx.x;
    for (int i = tid; i < 950; i += 256) {
        int ee = e0 + blockIdx.x * 2 + (i / 475);
        wl[i / 475][i % 475] = wig[(size_t)ee * 475 + (i % 475)];
    }
    __syncthreads();
    int le = tid >> 7, c = tid & 127;
    int el = blockIdx.x * 2 + le;       // chunk-local
    int e = e0 + el;                    // global
    int nd = (c < 64) ? snd[e] : rcv[e];
    int cc = c & 63;
    float msg[25];
#pragma unroll
    for (int k = 0; k < 25; k++) msg[k] = nf[(size_t)nd * 1600 + k * 64 + cc];
    const float* w = wl[le];
    size_t ebase = (size_t)el * 2432;
    size_t xbase = (size_t)el * 1536;
#pragma unroll
    for (int m = 0; m < 19; m++) {
        float r = 0.f;
#pragma unroll
        for (int k = 0; k < 25; k++) r += w[m * 25 + k] * msg[k];
        int a1c, xc;
        if (m < 5)       { a1c = m * 128;               xc = m * 128; }
        else if (m < 9)  { a1c = 640 + (m - 5) * 128;   xc = 640 + (m - 5) * 128; }
        else if (m < 13) { a1c = 1152 + (m - 9) * 128;  xc = 640 + (m - 9) * 128; }
        else if (m < 16) { a1c = 1664 + (m - 13) * 128; xc = 1152 + (m - 13) * 128; }
        else             { a1c = 2048 + (m - 16) * 128; xc = 1152 + (m - 16) * 128; }
        float sc = bf2f(xe[xbase + xc + c]);
        A1[ebase + a1c + c] = f2bf(r * sc);
    }
}

// ---------------- attention logits + segment max ----------------
__global__ __launch_bounds__(256) void k_logits(const u16* __restrict__ Y0, const int* __restrict__ rcv,
                                                const float* __restrict__ g, const float* __restrict__ b,
                                                const float* __restrict__ adot,
                                                float* __restrict__ logits, u32* __restrict__ nmax) {
    int e = blockIdx.x;
    int tid = threadIdx.x;
    int h = tid >> 5, c = tid & 31;
    float x = bf2f(Y0[(size_t)e * 640 + 320 + h * 32 + c]);
    float s = x, s2 = x * x;
#pragma unroll
    for (int o = 16; o; o >>= 1) { s += __shfl_xor(s, o); s2 += __shfl_xor(s2, o); }
    float mu = s * (1.f / 32.f);
    float var = s2 * (1.f / 32.f) - mu * mu;
    float rs = rsqrtf(var + 1e-5f);
    float a = (x - mu) * rs * g[c] + b[c];
    float f = 0.6f * a + 0.4f * a * (2.f * sigmoidf_(a) - 1.f);
    float l = f * adot[h * 32 + c];
#pragma unroll
    for (int o = 16; o; o >>= 1) l += __shfl_xor(l, o);
    if (c == 0) {
        logits[e * 8 + h] = l;
        atomicMax(&nmax[rcv[e] * 8 + h], encf(l));
    }
}

__global__ void k_expsum(const float* __restrict__ logits, const int* __restrict__ rcv,
                         const u32* __restrict__ nmax, float* __restrict__ ealpha, float* __restrict__ nsum) {
    int idx = blockIdx.x * 256 + threadIdx.x;
    if (idx >= E_EDGES * 8) return;
    int e = idx >> 3, h = idx & 7;
    int r = rcv[e];
    float amax = decf(nmax[r * 8 + h]);
    if (!(amax > -1e38f && amax < 1e38f)) amax = 0.f;
    float v = __expf(logits[idx] - amax);
    ealpha[idx] = v;
    atomicAdd(&nsum[r * 8 + h], v);
}

// ---------------- grid round-trip via MFMA ----------------
#define GR_XS_STR 40
#define GR_T1_STR 136
__global__ __launch_bounds__(256) void k_grid_mfma(
    const u16* __restrict__ Y0, const u16* __restrict__ Y1, const u16* __restrict__ Y2,
    const u16* __restrict__ tgP, const u16* __restrict__ fgP, u16* __restrict__ A2) {
    __shared__ u16 Xs[128 * GR_XS_STR];
    __shared__ u16 T1s[128 * GR_T1_STR];
    int tid = threadIdx.x;
    int e0 = blockIdx.x * 2;
    // zero T1s pad cols 112..127
    {
        int row = tid >> 1;
        uint4 z = {0, 0, 0, 0};
        *(uint4*)(&T1s[row * GR_T1_STR + 112 + (tid & 1) * 8]) = z;
    }
    // stage Xs[row][m] via uint4 loads
#pragma unroll
    for (int it = 0; it < 2; it++) {
        int i = tid + it * 256;
        int le = i >> 8;
        int m = (i >> 3) & 31;
        int c0 = (i & 7) << 3;
        int e = e0 + le;
        uint4 v = {0, 0, 0, 0};
        if (m < 5)       v = *(const uint4*)(&Y0[(size_t)e * 640 + m * 64 + c0]);
        else if (m < 13) v = *(const uint4*)(&Y1[(size_t)e * 512 + (m - 5) * 64 + c0]);
        else if (m < 19) v = *(const uint4*)(&Y2[(size_t)e * 384 + (m - 13) * 64 + c0]);
        const u16* pv = (const u16*)&v;
        int rbase = le * 64 + c0;
#pragma unroll
        for (int j = 0; j < 8; j++)
            Xs[(rbase + j) * GR_XS_STR + m] = pv[j];
    }
    __syncthreads();
    int wave = tid >> 6, lane = tid & 63;
    int wr = wave * 32;
    int ln = lane & 15, q = lane >> 4;
    // GEMM1: single K-step (K=32)
    short8 a0 = *(const short8*)(&Xs[(wr + ln) * GR_XS_STR + q * 8]);
    short8 a1 = *(const short8*)(&Xs[(wr + 16 + ln) * GR_XS_STR + q * 8]);
    floatx4 acc1[2][7];
#pragma unroll
    for (int pt = 0; pt < 7; pt++) {
        short8 b = *(const short8*)(&tgP[(size_t)(pt * 16 + ln) * 32 + q * 8]);
        acc1[0][pt] = __builtin_amdgcn_mfma_f32_16x16x32_bf16(a0, b, floatx4{0.f, 0.f, 0.f, 0.f}, 0, 0, 0);
        acc1[1][pt] = __builtin_amdgcn_mfma_f32_16x16x32_bf16(a1, b, floatx4{0.f, 0.f, 0.f, 0.f}, 0, 0, 0);
    }
    // silu -> T1s (skip pad cols >= 100: pt==6 && ln>=4)
#pragma unroll
    for (int rt = 0; rt < 2; rt++)
#pragma unroll
        for (int pt = 0; pt < 7; pt++) {
            bool pad = (pt == 6) && (ln >= 4);
#pragma unroll
            for (int r = 0; r < 4; r++) {
                int row = wr + rt * 16 + q * 4 + r;
                T1s[row * GR_T1_STR + pt * 16 + ln] = pad ? (u16)0 : f2bf(siluf_(acc1[rt][pt][r]));
            }
        }
    __syncthreads();
    // GEMM2: K=128 (4 steps)
    floatx4 acc2[2][2];
    acc2[0][0] = floatx4{0.f, 0.f, 0.f, 0.f}; acc2[0][1] = floatx4{0.f, 0.f, 0.f, 0.f};
    acc2[1][0] = floatx4{0.f, 0.f, 0.f, 0.f}; acc2[1][1] = floatx4{0.f, 0.f, 0.f, 0.f};
#pragma unroll
    for (int ks = 0; ks < 4; ks++) {
        short8 c0 = *(const short8*)(&T1s[(wr + ln) * GR_T1_STR + ks * 32 + q * 8]);
        short8 c1 = *(const short8*)(&T1s[(wr + 16 + ln) * GR_T1_STR + ks * 32 + q * 8]);
#pragma unroll
        for (int ct = 0; ct < 2; ct++) {
            short8 b = *(const short8*)(&fgP[(size_t)(ct * 16 + ln) * 128 + ks * 32 + q * 8]);
            acc2[0][ct] = __builtin_amdgcn_mfma_f32_16x16x32_bf16(c0, b, acc2[0][ct], 0, 0, 0);
            acc2[1][ct] = __builtin_amdgcn_mfma_f32_16x16x32_bf16(c1, b, acc2[1][ct], 0, 0, 0);
        }
    }
    // direct store: lane holds col m'=ct*16+ln, rows q*4+r -> 4 consecutive c in A2
#pragma unroll
    for (int rt = 0; rt < 2; rt++) {
        int row = wr + rt * 16 + q * 4;
        int e = e0 + (row >> 6), c = row & 63;
#pragma unroll
        for (int ct = 0; ct < 2; ct++) {
            int mp = ct * 16 + ln;
            if (mp >= 1 && mp < 19) {
                uint2 pv;
                pv.x = (u32)f2bf(acc2[rt][ct][0]) | ((u32)f2bf(acc2[rt][ct][1]) << 16);
                pv.y = (u32)f2bf(acc2[rt][ct][2]) | ((u32)f2bf(acc2[rt][ct][3]) << 16);
                *(uint2*)(&A2[(size_t)e * 1216 + mp * 64 + c]) = pv;
            }
        }
    }
    // m=0 gate row
    if (tid < 128) {
        int e = e0 + (tid >> 6), c = tid & 63;
        float gate = bf2f(Y0[(size_t)e * 640 + 576 + c]);
        A2[(size_t)e * 1216 + c] = f2bf(siluf_(gate));
    }
}

// ---------------- attention scale + wigner^T + segment-sum into node (chunked) ----------------
__global__ __launch_bounds__(256) void k_scatter(const u16* __restrict__ Z0, const u16* __restrict__ Z1,
                                                 const u16* __restrict__ Z2, const float* __restrict__ wig,
                                                 const float* __restrict__ ealpha, const float* __restrict__ nsum,
                                                 const int* __restrict__ rcv, float* __restrict__ node, int e0) {
    __shared__ float wl[2][475];
    int tid = threadIdx.x;
    for (int i = tid; i < 950; i += 256) {
        int ee = e0 + blockIdx.x * 2 + (i / 475);
        wl[i / 475][i % 475] = wig[(size_t)ee * 475 + (i % 475)];
    }
    __syncthreads();
    int le = tid >> 7, c = tid & 127;
    int el = blockIdx.x * 2 + le;
    int e = e0 + el;
    int r = rcv[e];
    int h = c >> 4;
    float al = ealpha[e * 8 + h] / (nsum[r * 8 + h] + 1e-16f);
    float s[19];
#pragma unroll
    for (int m = 0; m < 19; m++) {
        float v;
        if (m < 5)       v = bf2f(Z0[(size_t)el * 640 + m * 128 + c]);
        else if (m < 13) v = bf2f(Z1[(size_t)el * 1024 + (m - 5) * 128 + c]);
        else             v = bf2f(Z2[(size_t)el * 768 + (m - 13) * 128 + c]);
        s[m] = v * al;
    }
    const float* w = wl[le];
    float* nb = node + (size_t)r * 3200 + c;
#pragma unroll
    for (int k = 0; k < 25; k++) {
        float acc = 0.f;
#pragma unroll
        for (int m = 0; m < 19; m++) acc += w[m * 25 + k] * s[m];
        atomicAdd(&nb[k * 128], acc);
    }
}

// ---------------- final projection via MFMA ----------------
// grid (32 n-tiles, 25 k). Block: M=128 n-rows, N=64 d, K=128 c.
// A = node (f32, stride 3200) -> bf16 LDS; B = pwTb[l] (64x128 bf16).
#define PJ_STR 136
__global__ __launch_bounds__(256) void k_proj_mfma(
    const float* __restrict__ node, const u16* __restrict__ pwTb,
    const float* __restrict__ pb, float* __restrict__ out) {
    __shared__ u16 As[128 * PJ_STR];
    __shared__ u16 Bs[64 * PJ_STR];
    int tid = threadIdx.x;
    int n0 = blockIdx.x * 128;
    int k = blockIdx.y;
    int l = (int)sqrtf((float)k + 0.5f);
    // stage A: 128 rows x 128 c f32 -> bf16; thread i handles row=i>>5, c0=(i&31)*4
#pragma unroll
    for (int it = 0; it < 16; it++) {
        int i = tid + it * 256;
        int row = i >> 5;
        int c0 = (i & 31) << 2;
        float4 v = *(const float4*)(&node[(size_t)(n0 + row) * 3200 + k * 128 + c0]);
        u16* d = &As[row * PJ_STR + c0];
        d[0] = f2bf(v.x); d[1] = f2bf(v.y); d[2] = f2bf(v.z); d[3] = f2bf(v.w);
    }
    // stage B: 64 rows (d) x 128 c bf16, 16B chunks
    const u16* pw = pwTb + (size_t)l * 8192;
#pragma unroll
    for (int jt = 0; jt < 4; jt++) {
        int j = tid + jt * 256;
        int d = j >> 4;
        int c0 = (j & 15) << 3;
        *(uint4*)(&Bs[d * PJ_STR + c0]) = *(const uint4*)(&pw[d * 128 + c0]);
    }
    __syncthreads();
    int wave = tid >> 6, lane = tid & 63;
    int wr = wave * 32;
    int ln = lane & 15, q = lane >> 4;
    floatx4 acc[2][4];
#pragma unroll
    for (int i = 0; i < 2; i++)
#pragma unroll
        for (int j = 0; j < 4; j++) acc[i][j] = floatx4{0.f, 0.f, 0.f, 0.f};
#pragma unroll
    for (int ks = 0; ks < 4; ks++) {
        short8 a0 = *(const short8*)(&As[(wr + ln) * PJ_STR + ks * 32 + q * 8]);
        short8 a1 = *(const short8*)(&As[(wr + 16 + ln) * PJ_STR + ks * 32 + q * 8]);
#pragma unroll
        for (int j = 0; j < 4; j++) {
            short8 b = *(const short8*)(&Bs[(j * 16 + ln) * PJ_STR + ks * 32 + q * 8]);
            acc[0][j] = __builtin_amdgcn_mfma_f32_16x16x32_bf16(a0, b, acc[0][j], 0, 0, 0);
            acc[1][j] = __builtin_amdgcn_mfma_f32_16x16x32_bf16(a1, b, acc[1][j], 0, 0, 0);
        }
    }
    // epilogue: row=wr+rt*16+q*4+r -> n; col d=j*16+ln; +pb at k==0
#pragma unroll
    for (int rt = 0; rt < 2; rt++)
#pragma unroll
        for (int j = 0; j < 4; j++) {
            int d = j * 16 + ln;
            float bv = (k == 0) ? pb[d] : 0.f;
#pragma unroll
            for (int r = 0; r < 4; r++) {
                int n = n0 + wr + rt * 16 + q * 4 + r;
                out[(size_t)n * 1600 + k * 64 + d] = acc[rt][j][r] + bv;
            }
        }
}

extern "C" void kernel_launch(void* const* d_in, const int* in_sizes, int n_in,
                              void* d_out, int out_size, void* d_ws, size_t ws_size,
                              hipStream_t stream) {
    const float* nf      = (const float*)d_in[0];
    const int* species   = (const int*)d_in[1];
    const float* dist    = (const float*)d_in[2];
    const int* snd       = (const int*)d_in[3];
    const int* rcv       = (const int*)d_in[4];
    const float* wig     = (const float*)d_in[5];
    const float* semb    = (const float*)d_in[6];
    const float* remb    = (const float*)d_in[7];
    const float* rad_w1  = (const float*)d_in[8];
    const float* rad_b1  = (const float*)d_in[9];
    const float* rad_g1  = (const float*)d_in[10];
    const float* rad_be1 = (const float*)d_in[11];
    const float* rad_w2  = (const float*)d_in[12];
    const float* rad_b2  = (const float*)d_in[13];
    const float* rad_g2  = (const float*)d_in[14];
    const float* rad_be2 = (const float*)d_in[15];
    const float* rad_w3  = (const float*)d_in[16];
    const float* rad_b3  = (const float*)d_in[17];
    const float* c1_w0   = (const float*)d_in[18];
    const float* c1_b0   = (const float*)d_in[19];
    const float* c1_wm1  = (const float*)d_in[20];
    const float* c1_wm2  = (const float*)d_in[21];
    const float* aln_g   = (const float*)d_in[22];
    const float* aln_b   = (const float*)d_in[23];
    const float* adot    = (const float*)d_in[24];
    const float* to_grid = (const float*)d_in[25];
    const float* from_grid=(const float*)d_in[26];
    const float* c2_w0   = (const float*)d_in[27];
    const float* c2_b0   = (const float*)d_in[28];
    const float* c2_wm1  = (const float*)d_in[29];
    const float* c2_wm2  = (const float*)d_in[30];
    const float* proj_w  = (const float*)d_in[31];
    const float* proj_b  = (const float*)d_in[32];

    char* ws = (char*)d_ws;
    size_t off = 0;
    auto take = [&](size_t bytes) -> char* {
        char* p = ws + off;
        off += (bytes + 255) & ~(size_t)255;
        return p;
    };
    // fixed section
    u16* w_rad1T  = (u16*)take(64 * 192 * 2);
    u16* w_rad2T  = (u16*)take(64 * 64 * 2);
    u16* w_rad3T  = (u16*)take(1536 * 64 * 2);
    u16* w_c1w0T  = (u16*)take(640 * 640 * 2);
    u16* w_c1m1T  = (u16*)take((size_t)512 * 1024 * 2);
    u16* w_c1m2T  = (u16*)take((size_t)384 * 768 * 2);
    u16* w_c2w0T  = (u16*)take((size_t)640 * 320 * 2);
    u16* w_c2m1T  = (u16*)take((size_t)1024 * 512 * 2);
    u16* w_c2m2T  = (u16*)take((size_t)768 * 384 * 2);
    u16* w_tgP    = (u16*)take(112 * 32 * 2);
    u16* w_fgP    = (u16*)take(32 * 128 * 2);
    u16* w_pwT    = (u16*)take(5 * 8192 * 2);
    float* logits = (float*)take((size_t)E_EDGES * 8 * 4);
    float* ealpha = (float*)take((size_t)E_EDGES * 8 * 4);
    u32* nmax     = (u32*)take((size_t)N_NODES_C * 8 * 4);
    float* nsum   = (float*)take((size_t)N_NODES_C * 8 * 4);
    float* node   = (float*)take((size_t)N_NODES_C * 3200 * 4);
    u16* a_h2     = (u16*)take((size_t)E_EDGES * 64 * 2);
    // arena — aliased by phase
    char* arena   = take(173015040);
    if (off > ws_size) {  // diagnostic: paint output so the failure mode is identifiable
        k_diag<<<(out_size + 255) / 256, 256, 0, stream>>>((float*)d_out, out_size);
        return;
    }

    u16* a_ee   = (u16*)(arena + 0);           // radial phase
    u16* a_ypre = (u16*)(arena + 9437184);
    u16* a_h1   = (u16*)(arena + 12582912);
    u16* a_xe   = (u16*)(arena + 0);           // per-chunk (EC,1536); radial staging dead
    u16* a_A1   = (u16*)(arena + 37748736);    // per-chunk (EC,2432)
    u16* a_Y0   = (u16*)(arena + 97517568);    // full (E,640)
    u16* a_Y1   = (u16*)(arena + 128974848);   // full (E,512)
    u16* a_Y2   = (u16*)(arena + 154140672);   // full (E,384) -> arena end
    u16* a_A2   = (u16*)(arena + 0);           // full (E,1216); xe/A1 dead
    u16* a_Z0   = (u16*)(arena + 59768832);    // per-chunk (EC,640)
    u16* a_Z1   = (u16*)(arena + 75497472);    // per-chunk (EC,1024)
    u16* a_Z2   = (u16*)(arena + 100663296);   // per-chunk (EC,768); overlaps dead Y0 region

    // ---- weight prep ----
    k_transpose<<<48, 256, 0, stream>>>(rad_w1, w_rad1T, 192, 64);
    k_transpose<<<16, 256, 0, stream>>>(rad_w2, w_rad2T, 64, 64);
    k_transpose<<<384, 256, 0, stream>>>(rad_w3, w_rad3T, 64, 1536);
    k_transpose<<<1600, 256, 0, stream>>>(c1_w0, w_c1w0T, 640, 640);
    k_transpose<<<800, 256, 0, stream>>>(c2_w0, w_c2w0T, 320, 640);
    k_combine<<<2048, 256, 0, stream>>>(c1_wm1, w_c1m1T, 512, 256);
    k_combine<<<1152, 256, 0, stream>>>(c1_wm2, w_c1m2T, 384, 192);
    k_combine<<<2048, 256, 0, stream>>>(c2_wm1, w_c2m1T, 256, 512);
    k_combine<<<1152, 256, 0, stream>>>(c2_wm2, w_c2m2T, 192, 384);
    k_packgrid<<<30, 256, 0, stream>>>(to_grid, from_grid, w_tgP, w_fgP);
    for (int l = 0; l < 5; l++)
        k_transpose<<<32, 256, 0, stream>>>(proj_w + (size_t)l * 8192, w_pwT + (size_t)l * 8192, 128, 64);
    k_init<<<128, 256, 0, stream>>>(nmax, nsum, N_NODES_C * 8);
    hipMemsetAsync(node, 0, (size_t)N_NODES_C * 3200 * 4, stream);

    // ---- radial MLP (full E) ----
    k_ee<<<(E_EDGES * 192 + 255) / 256, 256, 0, stream>>>(dist, species, snd, rcv, semb, remb, a_ee);
    k_gemm<<<dim3(192, 1), 256, 0, stream>>>(a_ee, 192, w_rad1T, 192, a_ypre, 64, 64, 192, rad_b1);
    k_ln_silu<<<6144, 256, 0, stream>>>(a_ypre, a_h1, rad_g1, rad_be1);
    k_gemm<<<dim3(192, 1), 256, 0, stream>>>(a_h1, 64, w_rad2T, 64, a_ypre, 64, 64, 64, rad_b2);
    k_ln_silu<<<6144, 256, 0, stream>>>(a_ypre, a_h2, rad_g2, rad_be2);

    // ---- chunked: x_edge gemm -> rotate -> conv1 ----
    for (int c = 0; c < 2; c++) {
        int e0 = c * EC;
        k_gemm<<<dim3(96, 12), 256, 0, stream>>>(a_h2 + (size_t)e0 * 64, 64, w_rad3T, 64,
                                                 a_xe, 1536, 1536, 64, rad_b3);
        k_rotate<<<EC / 2, 256, 0, stream>>>(nf, wig, snd, rcv, a_xe, a_A1, e0);
        k_gemm<<<dim3(96, 5), 256, 0, stream>>>(a_A1, 2432, w_c1w0T, 640,
                                                a_Y0 + (size_t)e0 * 640, 640, 640, 640, c1_b0);
        k_gemm<<<dim3(96, 4), 256, 0, stream>>>(a_A1 + 640, 2432, w_c1m1T, 1024,
                                                a_Y1 + (size_t)e0 * 512, 512, 512, 1024, nullptr);
        k_gemm<<<dim3(96, 3), 256, 0, stream>>>(a_A1 + 1664, 2432, w_c1m2T, 768,
                                                a_Y2 + (size_t)e0 * 384, 384, 384, 768, nullptr);
    }

    // ---- attention softmax pieces ----
    k_logits<<<E_EDGES, 256, 0, stream>>>(a_Y0, rcv, aln_g, aln_b, adot, logits, nmax);
    k_expsum<<<(E_EDGES * 8 + 255) / 256, 256, 0, stream>>>(logits, rcv, nmax, ealpha, nsum);

    // ---- grid nonlinearity -> packed A2 (full E, MFMA) ----
    k_grid_mfma<<<E_EDGES / 2, 256, 0, stream>>>(a_Y0, a_Y1, a_Y2, w_tgP, w_fgP, a_A2);

    // ---- chunked: conv2 -> scatter ----
    for (int c = 0; c < 2; c++) {
        int e0 = c * EC;
        k_gemm<<<dim3(96, 5), 256, 0, stream>>>(a_A2 + (size_t)e0 * 1216, 1216, w_c2w0T, 320,
                                                a_Z0, 640, 640, 320, c2_b0);
        k_gemm<<<dim3(96, 8), 256, 0, stream>>>(a_A2 + (size_t)e0 * 1216 + 320, 1216, w_c2m1T, 512,
                                                a_Z1, 1024, 1024, 512, nullptr);
        k_gemm<<<dim3(96, 6), 256, 0, stream>>>(a_A2 + (size_t)e0 * 1216 + 832, 1216, w_c2m2T, 384,
                                                a_Z2, 768, 768, 384, nullptr);
        k_scatter<<<EC / 2, 256, 0, stream>>>(a_Z0, a_Z1, a_Z2, wig, ealpha, nsum, rcv, node, e0);
    }

    // ---- output projection (MFMA) ----
    k_proj_mfma<<<dim3(32, 25), 256, 0, stream>>>(node, w_pwT, proj_b, (float*)d_out);
}